// Round 12
// baseline (1203.342 us; speedup 1.0000x reference)
//
#include <hip/hip_runtime.h>

#define NN 2048
#define DDIM 128
#define NHEAD 4
#define DH 32
#define NL 6

typedef __attribute__((ext_vector_type(8))) __bf16 bf16x8;
typedef __attribute__((ext_vector_type(4))) float f32x4;

__device__ __forceinline__ unsigned int f2bf(float x) {
  unsigned int u = __float_as_uint(x);
  u += 0x7fff + ((u >> 16) & 1);   // RNE
  return u >> 16;
}
__device__ __forceinline__ unsigned int pk2(float a, float b) {
  return f2bf(a) | (f2bf(b) << 16);
}
__device__ __forceinline__ float bf2f(unsigned short u) {
  return __uint_as_float(((unsigned int)u) << 16);
}

// ---------------------------------------------------------------------------
// Fused setup: 790 blocks.
//   0..671  : weight cast fp32->bf16 (Wqkv | Wb2 | Wmix low-k)
//   672..719: Wmix high-k = W1b @ Wm + b1 fold
//   720..783: desc transpose/cast + fp32 residual copy
//   784..789: zero per-layer stats SgAll[6][1024] + counters cnt[6][256]
// ---------------------------------------------------------------------------
__global__ __launch_bounds__(256) void setup_kernel(
    const float* __restrict__ Wq, const float* __restrict__ Wk,
    const float* __restrict__ Wv, const float* __restrict__ Wm,
    const float* __restrict__ W1, const float* __restrict__ W2,
    const float* __restrict__ bmv, const float* __restrict__ b1,
    const float* __restrict__ desc0, const float* __restrict__ desc1,
    unsigned short* __restrict__ Wqkv, unsigned short* __restrict__ Wb2,
    unsigned short* __restrict__ Wmix, float* __restrict__ b1m,
    unsigned short* __restrict__ dT0, unsigned short* __restrict__ dT1,
    float* __restrict__ o0, float* __restrict__ o1,
    float* __restrict__ SgAll, float* __restrict__ cntAll) {
  __shared__ __align__(16) unsigned char ARENA[17408];
  const int bid = blockIdx.x;
  const int t = threadIdx.x;

  if (bid < 672) {
    int idx = (bid * 256 + t) * 4;
    if (idx >= 688128) return;
    const float* src; unsigned short* dst; int soff, doff;
    if (idx < 98304)       { src = Wq; soff = idx; dst = Wqkv; doff = idx; }
    else if (idx < 196608) { src = Wk; soff = idx - 98304; dst = Wqkv; doff = idx; }
    else if (idx < 294912) { src = Wv; soff = idx - 196608; dst = Wqkv; doff = idx; }
    else if (idx < 491520) { src = W2; soff = idx - 294912; dst = Wb2; doff = soff; }
    else {
      int f = idx - 491520;
      int l = f >> 15, rem = f & 32767;
      int i = rem >> 7, c = rem & 127;
      src = W1; soff = (l << 16) + (i << 8) + c;
      dst = Wmix; doff = (l << 16) + (i << 8) + c;
    }
    float4 v = *(const float4*)&src[soff];
    uint2 p = { pk2(v.x, v.y), pk2(v.z, v.w) };
    *(uint2*)&dst[doff] = p;
  } else if (bid < 720) {
    const int b = bid - 672;
    const int jb = b & 1, ib = (b >> 1) & 3, l = b >> 3;
    const int bj = jb * 64, bi = ib * 64;
    float* Ws = (float*)ARENA;            // [32][65]
    float* Xs = (float*)ARENA + 2080;     // [32][64]
    const int ti = (t >> 4) << 2;
    const int tj = (t & 15) << 2;
    float acc[4][4] = {{0.f}};
    for (int k0 = 0; k0 < 128; k0 += 32) {
#pragma unroll
      for (int i = 0; i < 8; ++i) {
        int e = t + i * 256;
        int ii = e >> 5, kk = e & 31;
        Ws[kk * 65 + ii] = W1[(size_t)(l << 16) + (bi + ii) * 256 + 128 + k0 + kk];
      }
#pragma unroll
      for (int i = 0; i < 2; ++i) {
        int e = t + i * 256;
        int r = e >> 4, c4 = e & 15;
        *(float4*)&Xs[r * 64 + c4 * 4] =
            *(const float4*)&Wm[(size_t)l * 16384 + (k0 + r) * 128 + bj + c4 * 4];
      }
      __syncthreads();
#pragma unroll
      for (int kk = 0; kk < 32; ++kk) {
        float a[4];
        a[0] = Ws[kk * 65 + ti]; a[1] = Ws[kk * 65 + ti + 1];
        a[2] = Ws[kk * 65 + ti + 2]; a[3] = Ws[kk * 65 + ti + 3];
        float4 b4 = *(const float4*)&Xs[kk * 64 + tj];
        float bb[4] = {b4.x, b4.y, b4.z, b4.w};
#pragma unroll
        for (int i = 0; i < 4; ++i)
#pragma unroll
          for (int j = 0; j < 4; ++j) acc[i][j] += a[i] * bb[j];
      }
      __syncthreads();
    }
#pragma unroll
    for (int i = 0; i < 4; ++i) {
      uint2 p = { pk2(acc[i][0], acc[i][1]), pk2(acc[i][2], acc[i][3]) };
      *(uint2*)&Wmix[(size_t)(l << 16) + (bi + ti + i) * 256 + 128 + bj + tj] = p;
    }
    if (jb == 0 && ib == 0) {
      float a = b1[l * 256 + t];
      const float* wr = &W1[(size_t)(l << 16) + t * 256 + 128];
      const float* bp = &bmv[l * 128];
      for (int k = 0; k < 128; k += 4)
        a += wr[k] * bp[k] + wr[k + 1] * bp[k + 1] + wr[k + 2] * bp[k + 2] + wr[k + 3] * bp[k + 3];
      b1m[l * 256 + t] = a;
    }
  } else if (bid < 784) {
    const int b = bid - 720;
    const float* D = (b >> 5) ? desc1 : desc0;
    unsigned short* T = (b >> 5) ? dT1 : dT0;
    float* O = (b >> 5) ? o1 : o0;
    const int n0 = (b & 31) * 64;
    unsigned short* L = (unsigned short*)ARENA;   // [64][136]
#pragma unroll
    for (int i = 0; i < 8; ++i) {
      int idx = t + i * 256;
      int c = idx >> 4, nj = (idx & 15) * 4;
      float4 v = *(const float4*)&D[(size_t)c * NN + n0 + nj];
      *(float4*)&O[(size_t)c * NN + n0 + nj] = v;
      L[(nj + 0) * 136 + c] = (unsigned short)f2bf(v.x);
      L[(nj + 1) * 136 + c] = (unsigned short)f2bf(v.y);
      L[(nj + 2) * 136 + c] = (unsigned short)f2bf(v.z);
      L[(nj + 3) * 136 + c] = (unsigned short)f2bf(v.w);
    }
    __syncthreads();
#pragma unroll
    for (int i = 0; i < 4; ++i) {
      int idx = t + i * 256;
      int n = idx >> 4, cj = (idx & 15) * 8;
      uint4 v = *(const uint4*)&L[n * 136 + cj];
      *(uint4*)&T[(size_t)(n0 + n) * 128 + cj] = v;
    }
  } else {
    const int b = bid - 784;   // layer index
    float4 z = make_float4(0.f, 0.f, 0.f, 0.f);
    *(float4*)&SgAll[b * 1024 + t * 4] = z;
    if (t < 64) *(float4*)&cntAll[b * 256 + t * 4] = z;
  }
}

// ---------------------------------------------------------------------------
// Direct-fragment bf16 MFMA GEMM (R9). Tile 64M x 64N, 4 waves.
// Modes: 0=Q scaled  1=K transposed  2=V  4=mlp2(norm+relu B, residual)
// ---------------------------------------------------------------------------
struct MOp {
  const unsigned short* A;
  const float* bias;
  const unsigned short* B1;
  const unsigned short* B2;
  unsigned short* Cb;
  float* Cf;
  const float* Sp;
  int ldb, ldc, mode;
};
struct MOps8 { MOp op[8]; };

template <int K>
__global__ __launch_bounds__(256) void gemm_direct_kernel(MOps8 P) {
  const MOp g = P.op[blockIdx.z];
  const int t = threadIdx.x;
  const int w = t >> 6, lane = t & 63;
  const int col = lane & 15, Qd = lane >> 4;
  const int bm = blockIdx.y * 64;
  const int bn = blockIdx.x * 64;

  __shared__ float meanL[256], rstdL[256];

  if (g.mode == 4) {
    float s = g.Sp[t * 2], ss = g.Sp[t * 2 + 1];
    float mean = s * (1.0f / NN);
    float var = fmaxf(ss * (1.0f / NN) - mean * mean, 0.f);
    meanL[t] = mean;
    rstdL[t] = rsqrtf(var + 1e-5f);
  }
  __syncthreads();

  const int n = bn + w * 16 + col;
  f32x4 acc[4];
#pragma unroll
  for (int mt = 0; mt < 4; ++mt) acc[mt] = (f32x4){0.f, 0.f, 0.f, 0.f};

#pragma unroll
  for (int k0 = 0; k0 < K; k0 += 32) {
    bf16x8 af[4];
#pragma unroll
    for (int mt = 0; mt < 4; ++mt)
      af[mt] = *(const bf16x8*)&g.A[(size_t)(bm + mt * 16 + col) * K + k0 + Qd * 8];
    const unsigned short* Bp = g.B1;
    int kk = k0;
    if (g.B2 && k0 >= 128) { Bp = g.B2; kk = k0 - 128; }
    uint4 v = *(const uint4*)&Bp[(size_t)n * g.ldb + kk + Qd * 8];
    if (g.mode == 4) {
      float4 mA = *(const float4*)&meanL[k0 + Qd * 8];
      float4 mB = *(const float4*)&meanL[k0 + Qd * 8 + 4];
      float4 rA = *(const float4*)&rstdL[k0 + Qd * 8];
      float4 rB = *(const float4*)&rstdL[k0 + Qd * 8 + 4];
      union { uint4 q; unsigned short us[8]; } u;
      u.q = v;
      float x0 = fmaxf((bf2f(u.us[0]) - mA.x) * rA.x, 0.f);
      float x1 = fmaxf((bf2f(u.us[1]) - mA.y) * rA.y, 0.f);
      float x2 = fmaxf((bf2f(u.us[2]) - mA.z) * rA.z, 0.f);
      float x3 = fmaxf((bf2f(u.us[3]) - mA.w) * rA.w, 0.f);
      float x4 = fmaxf((bf2f(u.us[4]) - mB.x) * rB.x, 0.f);
      float x5 = fmaxf((bf2f(u.us[5]) - mB.y) * rB.y, 0.f);
      float x6 = fmaxf((bf2f(u.us[6]) - mB.z) * rB.z, 0.f);
      float x7 = fmaxf((bf2f(u.us[7]) - mB.w) * rB.w, 0.f);
      u.q.x = pk2(x0, x1); u.q.y = pk2(x2, x3);
      u.q.z = pk2(x4, x5); u.q.w = pk2(x6, x7);
      v = u.q;
    }
    union { uint4 q; bf16x8 b; } bc;
    bc.q = v;
#pragma unroll
    for (int mt = 0; mt < 4; ++mt)
      acc[mt] = __builtin_amdgcn_mfma_f32_16x16x32_bf16(af[mt], bc.b, acc[mt], 0, 0, 0);
  }

#pragma unroll
  for (int mt = 0; mt < 4; ++mt) {
    const int c0 = bm + mt * 16 + Qd * 4;
    const float b0 = g.bias[c0], b1 = g.bias[c0 + 1];
    const float b2 = g.bias[c0 + 2], b3 = g.bias[c0 + 3];
    f32x4 a = acc[mt];
    float v0 = a[0] + b0, v1 = a[1] + b1, v2 = a[2] + b2, v3 = a[3] + b3;
    if (g.mode <= 2) {
      if (g.mode == 0) {
        const float sc = 0.25503488f;  // 1/sqrt(32)*log2e
        v0 *= sc; v1 *= sc; v2 *= sc; v3 *= sc;
      }
      const int d = c0 >> 2;
      if (g.mode == 1) {
        g.Cb[((size_t)0 * NN + n) * 32 + d] = (unsigned short)f2bf(v0);
        g.Cb[((size_t)1 * NN + n) * 32 + d] = (unsigned short)f2bf(v1);
        g.Cb[((size_t)2 * NN + n) * 32 + d] = (unsigned short)f2bf(v2);
        g.Cb[((size_t)3 * NN + n) * 32 + d] = (unsigned short)f2bf(v3);
      } else {
        g.Cb[(size_t)(0 * 32 + d) * NN + n] = (unsigned short)f2bf(v0);
        g.Cb[(size_t)(1 * 32 + d) * NN + n] = (unsigned short)f2bf(v1);
        g.Cb[(size_t)(2 * 32 + d) * NN + n] = (unsigned short)f2bf(v2);
        g.Cb[(size_t)(3 * 32 + d) * NN + n] = (unsigned short)f2bf(v3);
      }
    } else {  // mode 4
      float* dp = g.Cf;
      float o0 = dp[(size_t)(c0 + 0) * NN + n] + v0;
      float o1 = dp[(size_t)(c0 + 1) * NN + n] + v1;
      float o2 = dp[(size_t)(c0 + 2) * NN + n] + v2;
      float o3 = dp[(size_t)(c0 + 3) * NN + n] + v3;
      dp[(size_t)(c0 + 0) * NN + n] = o0;
      dp[(size_t)(c0 + 1) * NN + n] = o1;
      dp[(size_t)(c0 + 2) * NN + n] = o2;
      dp[(size_t)(c0 + 3) * NN + n] = o3;
      uint2 pv = { pk2(o0, o1), pk2(o2, o3) };
      *(uint2*)&g.Cb[(size_t)n * g.ldc + c0] = pv;
    }
  }
}

// ---------------------------------------------------------------------------
// Merged attention + mlp1 (last-finisher). Grid (128 q-tiles of 16, 8 z).
// Attention = R9 single-pass online softmax, direct-fragment loads, wave-
// private key quarters. After mgT slice write: threadfence + per-(desc,qtile)
// counter; 4th finisher runs mlp1 for its 16 queries (reads dT + complete
// mgT, writes HT bf16, atomic stats into Sg).
// ---------------------------------------------------------------------------
struct AArgs {
  const unsigned short *Qb0, *Kt0, *Vb0, *Qb1, *Kt1, *Vb1;
  unsigned short *mgT0, *mgT1;
  const unsigned short *dT0, *dT1;
  unsigned short *HT0, *HT1;
  float *Sg0, *Sg1;
  const unsigned short* Wmx;   // [256][256] bf16
  const float* b1p;            // [256]
  int* cnt;                    // [256] zeroed per launch
  int cross;
};

__global__ __launch_bounds__(256, 4) void attn_mlp1_kernel(AArgs A) {
  const int z = blockIdx.y, desc = z >> 2, h = z & 3;
  const int t = threadIdx.x;
  const int wid = t >> 6, lane = t & 63;
  const int col = lane & 15, Qd = lane >> 4;
  const int qb = blockIdx.x * 16;

  const unsigned short* Qb = desc ? A.Qb1 : A.Qb0;
  const int s = A.cross ? (1 - desc) : desc;
  const unsigned short* Kt = s ? A.Kt1 : A.Kt0;
  const unsigned short* Vb = s ? A.Vb1 : A.Vb0;

  __shared__ __align__(16) unsigned short SM[7424];
  __shared__ int winflag;
  unsigned short* PW = SM + wid * 640;
  float* fS = (float*)(SM + 2560);

  bf16x8 bq;
  {
    union { unsigned short u[8]; bf16x8 v; } tmp;
#pragma unroll
    for (int j = 0; j < 8; ++j)
      tmp.u[j] = Qb[(size_t)(h * 32 + Qd * 8 + j) * NN + qb + col];
    bq = tmp.v;
  }

  f32x4 o0 = {0.f, 0.f, 0.f, 0.f}, o1 = {0.f, 0.f, 0.f, 0.f};
  float m = -1e30f, l = 0.f;

  const int kq = wid * 512;
#pragma unroll 2
  for (int it = 0; it < 16; ++it) {
    const int k0 = kq + it * 32;
    bf16x8 aK0 = *(const bf16x8*)&Kt[((size_t)h * NN + k0 + col) * 32 + Qd * 8];
    bf16x8 aK1 = *(const bf16x8*)&Kt[((size_t)h * NN + k0 + 16 + col) * 32 + Qd * 8];
    bf16x8 av0 = *(const bf16x8*)&Vb[(size_t)(h * 32 + col) * NN + k0 + Qd * 8];
    bf16x8 av1 = *(const bf16x8*)&Vb[(size_t)(h * 32 + 16 + col) * NN + k0 + Qd * 8];
    f32x4 z4 = {0.f, 0.f, 0.f, 0.f};
    f32x4 s0 = __builtin_amdgcn_mfma_f32_16x16x32_bf16(aK0, bq, z4, 0, 0, 0);
    f32x4 s1 = __builtin_amdgcn_mfma_f32_16x16x32_bf16(aK1, bq, z4, 0, 0, 0);
    float cm = fmaxf(fmaxf(fmaxf(s0[0], s0[1]), fmaxf(s0[2], s0[3])),
                     fmaxf(fmaxf(s1[0], s1[1]), fmaxf(s1[2], s1[3])));
    cm = fmaxf(cm, __shfl_xor(cm, 16));
    cm = fmaxf(cm, __shfl_xor(cm, 32));
    const float mn = fmaxf(m, cm);
    const float alpha = exp2f(m - mn);
    m = mn;
    float p00 = exp2f(s0[0] - mn), p01 = exp2f(s0[1] - mn);
    float p02 = exp2f(s0[2] - mn), p03 = exp2f(s0[3] - mn);
    float p10 = exp2f(s1[0] - mn), p11 = exp2f(s1[1] - mn);
    float p12 = exp2f(s1[2] - mn), p13 = exp2f(s1[3] - mn);
    float us = (p00 + p01) + (p02 + p03) + (p10 + p11) + (p12 + p13);
    us += __shfl_xor(us, 16);
    us += __shfl_xor(us, 32);
    l = l * alpha + us;
    uint2 w0 = { pk2(p00, p01), pk2(p02, p03) };
    uint2 w1 = { pk2(p10, p11), pk2(p12, p13) };
    *(uint2*)&PW[col * 40 + Qd * 4] = w0;
    *(uint2*)&PW[col * 40 + 16 + Qd * 4] = w1;
    bf16x8 pb = *(const bf16x8*)&PW[col * 40 + Qd * 8];
    o0 = o0 * alpha;
    o1 = o1 * alpha;
    o0 = __builtin_amdgcn_mfma_f32_16x16x32_bf16(av0, pb, o0, 0, 0, 0);
    o1 = __builtin_amdgcn_mfma_f32_16x16x32_bf16(av1, pb, o1, 0, 0, 0);
  }

  __syncthreads();
  *(float4*)&fS[wid * 576 + col * 36 + Qd * 4] =
      make_float4(o0[0], o0[1], o0[2], o0[3]);
  *(float4*)&fS[wid * 576 + col * 36 + 16 + Qd * 4] =
      make_float4(o1[0], o1[1], o1[2], o1[3]);
  if (Qd == 0) {
    fS[2304 + wid * 16 + col] = m;
    fS[2368 + wid * 16 + col] = l;
  }
  __syncthreads();
  {
    const int q16 = t >> 4, dg = t & 15;
    float m0 = fS[2304 + q16], m1 = fS[2304 + 16 + q16];
    float m2 = fS[2304 + 32 + q16], m3 = fS[2304 + 48 + q16];
    float M = fmaxf(fmaxf(m0, m1), fmaxf(m2, m3));
    float w0 = exp2f(m0 - M), w1 = exp2f(m1 - M);
    float w2 = exp2f(m2 - M), w3 = exp2f(m3 - M);
    float L = w0 * fS[2368 + q16] + w1 * fS[2368 + 16 + q16] +
              w2 * fS[2368 + 32 + q16] + w3 * fS[2368 + 48 + q16];
    float inv = 1.0f / L;
    unsigned short* T = desc ? A.mgT1 : A.mgT0;
    const int q = qb + q16;
#pragma unroll
    for (int r = 0; r < 2; ++r) {
      int d = dg * 2 + r;
      float v = (w0 * fS[0 * 576 + q16 * 36 + d] + w1 * fS[1 * 576 + q16 * 36 + d] +
                 w2 * fS[2 * 576 + q16 * 36 + d] + w3 * fS[3 * 576 + q16 * 36 + d]) * inv;
      T[(size_t)q * 128 + d * 4 + h] = (unsigned short)f2bf(v);
    }
  }

  // ---- last-finisher handoff ----
  __threadfence();
  __syncthreads();
  if (t == 0) {
    int old = atomicAdd(&A.cnt[desc * 128 + blockIdx.x], 1);
    winflag = (old == 3) ? 1 : 0;
  }
  __syncthreads();
  if (!winflag) return;
  __threadfence();  // acquire side: see other heads' mgT stores

  // ---- mlp1 for n in [qb, qb+16): wave wid owns rows wid*64..wid*64+64 ----
  const unsigned short* dT = desc ? A.dT1 : A.dT0;
  const unsigned short* mgT = desc ? A.mgT1 : A.mgT0;
  unsigned short* HT = desc ? A.HT1 : A.HT0;
  float* Sg = desc ? A.Sg1 : A.Sg0;
  const int n = qb + col;

  f32x4 acc[4];
#pragma unroll
  for (int mt = 0; mt < 4; ++mt) acc[mt] = (f32x4){0.f, 0.f, 0.f, 0.f};
#pragma unroll
  for (int k0 = 0; k0 < 256; k0 += 32) {
    const unsigned short* Bp = (k0 < 128) ? dT : mgT;
    const int kk = k0 & 127;
    union { uint4 q; bf16x8 b; } bc;
    bc.q = *(const uint4*)&Bp[(size_t)n * 128 + kk + Qd * 8];
#pragma unroll
    for (int mt = 0; mt < 4; ++mt) {
      bf16x8 af = *(const bf16x8*)&A.Wmx[(size_t)(wid * 64 + mt * 16 + col) * 256 + k0 + Qd * 8];
      acc[mt] = __builtin_amdgcn_mfma_f32_16x16x32_bf16(af, bc.b, acc[mt], 0, 0, 0);
    }
  }
#pragma unroll
  for (int mt = 0; mt < 4; ++mt) {
    const int c0 = wid * 64 + mt * 16 + Qd * 4;
    f32x4 a = acc[mt];
    float v0 = a[0] + A.b1p[c0], v1 = a[1] + A.b1p[c0 + 1];
    float v2 = a[2] + A.b1p[c0 + 2], v3 = a[3] + A.b1p[c0 + 3];
    uint2 pv = { pk2(v0, v1), pk2(v2, v3) };
    *(uint2*)&HT[(size_t)n * 256 + c0] = pv;
    float sA[4] = {v0, v1, v2, v3};
    float sQ[4] = {v0 * v0, v1 * v1, v2 * v2, v3 * v3};
#pragma unroll
    for (int r = 0; r < 4; ++r) {
#pragma unroll
      for (int off = 1; off < 16; off <<= 1) {
        sA[r] += __shfl_xor(sA[r], off);
        sQ[r] += __shfl_xor(sQ[r], off);
      }
    }
    if (col == 0) {
#pragma unroll
      for (int r = 0; r < 4; ++r) {
        atomicAdd(&Sg[(c0 + r) * 2], sA[r]);
        atomicAdd(&Sg[(c0 + r) * 2 + 1], sQ[r]);
      }
    }
  }
}

// ---------------------------------------------------------------------------
// Fused tail: mlp2(layer l) + QKV(layer l+1) (unchanged from R11).
// ---------------------------------------------------------------------------
struct FDesc {
  const unsigned short* HT; const float* Sp; float* outF; unsigned short* dT;
  unsigned short* Qb; unsigned short* Kt; unsigned short* Vb;
};
struct FArgs {
  FDesc d[2];
  const unsigned short *W2l, *Wql, *Wkl, *Wvl;
  const float *b2l, *bql, *bkl, *bvl;
};

__global__ __launch_bounds__(256) void fused_tail_kernel(FArgs F) {
  const FDesc g = F.d[blockIdx.y];
  const int t = threadIdx.x;
  const int w = t >> 6, lane = t & 63;
  const int col = lane & 15, Qd = lane >> 4;
  const int nb = blockIdx.x * 16;
  const int n = nb + col;

  __shared__ float meanL[256], rstdL[256];
  __shared__ __align__(16) unsigned short dTs[16 * 136];

  {
    float s = g.Sp[t * 2], ss = g.Sp[t * 2 + 1];
    float mean = s * (1.0f / NN);
    float var = fmaxf(ss * (1.0f / NN) - mean * mean, 0.f);
    meanL[t] = mean;
    rstdL[t] = rsqrtf(var + 1e-5f);
  }
  __syncthreads();

  f32x4 accA[2];
  accA[0] = (f32x4){0.f, 0.f, 0.f, 0.f};
  accA[1] = (f32x4){0.f, 0.f, 0.f, 0.f};
#pragma unroll
  for (int k0 = 0; k0 < 256; k0 += 32) {
    uint4 v = *(const uint4*)&g.HT[(size_t)n * 256 + k0 + Qd * 8];
    float4 mA = *(const float4*)&meanL[k0 + Qd * 8];
    float4 mB = *(const float4*)&meanL[k0 + Qd * 8 + 4];
    float4 rA = *(const float4*)&rstdL[k0 + Qd * 8];
    float4 rB = *(const float4*)&rstdL[k0 + Qd * 8 + 4];
    union { uint4 q; unsigned short us[8]; } u;
    u.q = v;
    float x0 = fmaxf((bf2f(u.us[0]) - mA.x) * rA.x, 0.f);
    float x1 = fmaxf((bf2f(u.us[1]) - mA.y) * rA.y, 0.f);
    float x2 = fmaxf((bf2f(u.us[2]) - mA.z) * rA.z, 0.f);
    float x3 = fmaxf((bf2f(u.us[3]) - mA.w) * rA.w, 0.f);
    float x4 = fmaxf((bf2f(u.us[4]) - mB.x) * rB.x, 0.f);
    float x5 = fmaxf((bf2f(u.us[5]) - mB.y) * rB.y, 0.f);
    float x6 = fmaxf((bf2f(u.us[6]) - mB.z) * rB.z, 0.f);
    float x7 = fmaxf((bf2f(u.us[7]) - mB.w) * rB.w, 0.f);
    u.q.x = pk2(x0, x1); u.q.y = pk2(x2, x3);
    u.q.z = pk2(x4, x5); u.q.w = pk2(x6, x7);
    union { uint4 q; bf16x8 b; } bc;
    bc.q = u.q;
#pragma unroll
    for (int mt = 0; mt < 2; ++mt) {
      bf16x8 af = *(const bf16x8*)&F.W2l[(size_t)(w * 32 + mt * 16 + col) * 256 + k0 + Qd * 8];
      accA[mt] = __builtin_amdgcn_mfma_f32_16x16x32_bf16(af, bc.b, accA[mt], 0, 0, 0);
    }
  }
#pragma unroll
  for (int mt = 0; mt < 2; ++mt) {
    const int c0 = w * 32 + mt * 16 + Qd * 4;
    f32x4 a = accA[mt];
    float o0 = g.outF[(size_t)(c0 + 0) * NN + n] + a[0] + F.b2l[c0 + 0];
    float o1 = g.outF[(size_t)(c0 + 1) * NN + n] + a[1] + F.b2l[c0 + 1];
    float o2 = g.outF[(size_t)(c0 + 2) * NN + n] + a[2] + F.b2l[c0 + 2];
    float o3 = g.outF[(size_t)(c0 + 3) * NN + n] + a[3] + F.b2l[c0 + 3];
    g.outF[(size_t)(c0 + 0) * NN + n] = o0;
    g.outF[(size_t)(c0 + 1) * NN + n] = o1;
    g.outF[(size_t)(c0 + 2) * NN + n] = o2;
    g.outF[(size_t)(c0 + 3) * NN + n] = o3;
    unsigned short s0 = (unsigned short)f2bf(o0), s1 = (unsigned short)f2bf(o1);
    unsigned short s2 = (unsigned short)f2bf(o2), s3 = (unsigned short)f2bf(o3);
    dTs[col * 136 + c0 + 0] = s0;
    dTs[col * 136 + c0 + 1] = s1;
    dTs[col * 136 + c0 + 2] = s2;
    dTs[col * 136 + c0 + 3] = s3;
    uint2 pv = { ((unsigned int)s0) | (((unsigned int)s1) << 16),
                 ((unsigned int)s2) | (((unsigned int)s3) << 16) };
    *(uint2*)&g.dT[(size_t)n * 128 + c0] = pv;
  }
  __syncthreads();

  f32x4 accB[6];
#pragma unroll
  for (int f = 0; f < 6; ++f) accB[f] = (f32x4){0.f, 0.f, 0.f, 0.f};
#pragma unroll
  for (int k0 = 0; k0 < 128; k0 += 32) {
    bf16x8 bq = *(const bf16x8*)&dTs[col * 136 + k0 + Qd * 8];
#pragma unroll
    for (int f = 0; f < 6; ++f) {
      const int idx = w * 6 + f;
      const int op = idx >> 3, mt = idx & 7;
      const unsigned short* W = (op == 0) ? F.Wql : (op == 1) ? F.Wkl : F.Wvl;
      bf16x8 af = *(const bf16x8*)&W[(size_t)(mt * 16 + col) * 128 + k0 + Qd * 8];
      accB[f] = __builtin_amdgcn_mfma_f32_16x16x32_bf16(af, bq, accB[f], 0, 0, 0);
    }
  }
#pragma unroll
  for (int f = 0; f < 6; ++f) {
    const int idx = w * 6 + f;
    const int op = idx >> 3, mt = idx & 7;
    const float* bias = (op == 0) ? F.bql : (op == 1) ? F.bkl : F.bvl;
    const int c0 = mt * 16 + Qd * 4;
    f32x4 a = accB[f];
    float v0 = a[0] + bias[c0], v1 = a[1] + bias[c0 + 1];
    float v2 = a[2] + bias[c0 + 2], v3 = a[3] + bias[c0 + 3];
    const int d = c0 >> 2;
    if (op == 0) {
      const float sc = 0.25503488f;  // 1/sqrt(32)*log2e
      v0 *= sc; v1 *= sc; v2 *= sc; v3 *= sc;
      g.Qb[(size_t)(0 * 32 + d) * NN + n] = (unsigned short)f2bf(v0);
      g.Qb[(size_t)(1 * 32 + d) * NN + n] = (unsigned short)f2bf(v1);
      g.Qb[(size_t)(2 * 32 + d) * NN + n] = (unsigned short)f2bf(v2);
      g.Qb[(size_t)(3 * 32 + d) * NN + n] = (unsigned short)f2bf(v3);
    } else if (op == 1) {
      g.Kt[((size_t)0 * NN + n) * 32 + d] = (unsigned short)f2bf(v0);
      g.Kt[((size_t)1 * NN + n) * 32 + d] = (unsigned short)f2bf(v1);
      g.Kt[((size_t)2 * NN + n) * 32 + d] = (unsigned short)f2bf(v2);
      g.Kt[((size_t)3 * NN + n) * 32 + d] = (unsigned short)f2bf(v3);
    } else {
      g.Vb[(size_t)(0 * 32 + d) * NN + n] = (unsigned short)f2bf(v0);
      g.Vb[(size_t)(1 * 32 + d) * NN + n] = (unsigned short)f2bf(v1);
      g.Vb[(size_t)(2 * 32 + d) * NN + n] = (unsigned short)f2bf(v2);
      g.Vb[(size_t)(3 * 32 + d) * NN + n] = (unsigned short)f2bf(v3);
    }
  }
}

// ---------------------------------------------------------------------------
extern "C" void kernel_launch(void* const* d_in, const int* in_sizes, int n_in,
                              void* d_out, int out_size, void* d_ws, size_t ws_size,
                              hipStream_t stream) {
  const float* desc0 = (const float*)d_in[0];
  const float* desc1 = (const float*)d_in[1];
  const float* Wq = (const float*)d_in[2];
  const float* bq = (const float*)d_in[3];
  const float* Wk = (const float*)d_in[4];
  const float* bk = (const float*)d_in[5];
  const float* Wv = (const float*)d_in[6];
  const float* bv = (const float*)d_in[7];
  const float* Wm = (const float*)d_in[8];
  const float* bmv = (const float*)d_in[9];
  const float* W1 = (const float*)d_in[10];
  const float* b1 = (const float*)d_in[11];
  const float* W2 = (const float*)d_in[12];
  const float* b2 = (const float*)d_in[13];

  float* out0 = (float*)d_out;
  float* out1 = out0 + (size_t)DDIM * NN;

  float* fws = (float*)d_ws;
  float* SgAll = fws;                  // 6 x 1024
  float* cntAll = SgAll + 6144;        // 6 x 256 (int)
  float* b1m = cntAll + 1536;          // 1536
  unsigned short* uws = (unsigned short*)(b1m + 1536);
  unsigned short* dT0 = uws;                     // 262144 each
  unsigned short* dT1 = uws + 1 * 262144;
  unsigned short* Qb0 = uws + 2 * 262144;
  unsigned short* Qb1 = uws + 3 * 262144;
  unsigned short* Kt0 = uws + 4 * 262144;
  unsigned short* Kt1 = uws + 5 * 262144;
  unsigned short* Vb0 = uws + 6 * 262144;
  unsigned short* Vb1 = uws + 7 * 262144;
  unsigned short* mgT0 = uws + 8 * 262144;
  unsigned short* mgT1 = uws + 9 * 262144;
  unsigned short* HT0 = uws + 10 * 262144;       // 524288
  unsigned short* HT1 = HT0 + 524288;            // 524288
  unsigned short* Wqkv = HT1 + 524288;           // 294912
  unsigned short* Wb2 = Wqkv + 294912;           // 196608
  unsigned short* Wmix = Wb2 + 196608;           // 393216

  setup_kernel<<<790, 256, 0, stream>>>(Wq, Wk, Wv, Wm, W1, W2, bmv, b1,
                                        desc0, desc1, Wqkv, Wb2, Wmix, b1m,
                                        dT0, dT1, out0, out1, SgAll, cntAll);

  // layer-0 QKV (standalone)
  {
    MOps8 Pq = {};
    Pq.op[0] = {Wqkv, bq, dT0, nullptr, Qb0, nullptr, nullptr, 128, 0, 0};
    Pq.op[1] = {Wqkv, bq, dT1, nullptr, Qb1, nullptr, nullptr, 128, 0, 0};
    Pq.op[2] = {Wqkv + 98304, bk, dT0, nullptr, Kt0, nullptr, nullptr, 128, 0, 1};
    Pq.op[3] = {Wqkv + 98304, bk, dT1, nullptr, Kt1, nullptr, nullptr, 128, 0, 1};
    Pq.op[4] = {Wqkv + 196608, bv, dT0, nullptr, Vb0, nullptr, nullptr, 128, 0, 2};
    Pq.op[5] = {Wqkv + 196608, bv, dT1, nullptr, Vb1, nullptr, nullptr, 128, 0, 2};
    gemm_direct_kernel<128><<<dim3(32, 2, 6), 256, 0, stream>>>(Pq);
  }

  for (int l = 0; l < NL; ++l) {
    const unsigned short* w2 = Wb2 + l * 32768;
    const float* b2p = b2 + (size_t)l * 128;
    float* Sg0 = SgAll + l * 1024;
    float* Sg1 = Sg0 + 512;

    AArgs A;
    A.Qb0 = Qb0; A.Kt0 = Kt0; A.Vb0 = Vb0;
    A.Qb1 = Qb1; A.Kt1 = Kt1; A.Vb1 = Vb1;
    A.mgT0 = mgT0; A.mgT1 = mgT1;
    A.dT0 = dT0; A.dT1 = dT1;
    A.HT0 = HT0; A.HT1 = HT1;
    A.Sg0 = Sg0; A.Sg1 = Sg1;
    A.Wmx = Wmix + l * 65536;
    A.b1p = b1m + (size_t)l * 256;
    A.cnt = (int*)(cntAll + l * 256);
    A.cross = l & 1;
    attn_mlp1_kernel<<<dim3(128, 8), 256, 0, stream>>>(A);

    if (l < NL - 1) {
      FArgs F;
      F.d[0] = {HT0, Sg0, out0, dT0, Qb0, Kt0, Vb0};
      F.d[1] = {HT1, Sg1, out1, dT1, Qb1, Kt1, Vb1};
      F.W2l = w2;
      F.Wql = Wqkv + (l + 1) * 16384;
      F.Wkl = Wqkv + 98304 + (l + 1) * 16384;
      F.Wvl = Wqkv + 196608 + (l + 1) * 16384;
      F.b2l = b2p;
      F.bql = bq + (size_t)(l + 1) * 128;
      F.bkl = bk + (size_t)(l + 1) * 128;
      F.bvl = bv + (size_t)(l + 1) * 128;
      fused_tail_kernel<<<dim3(128, 2), 256, 0, stream>>>(F);
    } else {
      MOps8 P2 = {};
      P2.op[0] = {w2, b2p, HT0, nullptr, dT0, out0, Sg0, 256, 128, 4};
      P2.op[1] = {w2, b2p, HT1, nullptr, dT1, out1, Sg1, 256, 128, 4};
      gemm_direct_kernel<256><<<dim3(32, 2, 2), 256, 0, stream>>>(P2);
    }
  }
}

// Round 13
// 422.816 us; speedup vs baseline: 2.8460x; 2.8460x over previous
//
#include <hip/hip_runtime.h>

#define NN 2048
#define DDIM 128
#define NHEAD 4
#define DH 32
#define NL 6

typedef __attribute__((ext_vector_type(8))) __bf16 bf16x8;
typedef __attribute__((ext_vector_type(4))) float f32x4;

__device__ __forceinline__ unsigned int f2bf(float x) {
  unsigned int u = __float_as_uint(x);
  u += 0x7fff + ((u >> 16) & 1);   // RNE
  return u >> 16;
}
__device__ __forceinline__ unsigned int pk2(float a, float b) {
  return f2bf(a) | (f2bf(b) << 16);
}
__device__ __forceinline__ float bf2f(unsigned short u) {
  return __uint_as_float(((unsigned int)u) << 16);
}

// ---------------------------------------------------------------------------
// Fused setup: 790 blocks.
//   0..671  : weight cast fp32->bf16 (Wqkv | Wb2 | Wmix low-k)
//   672..719: Wmix high-k = W1b @ Wm + b1 fold
//   720..783: desc transpose/cast + fp32 residual copy + LAYER-0 QKV
//             (dT rows for the block's 64 queries are in LDS; A-frags are
//              converted from fp32 weights on the fly, same RNE rounding)
//   784..789: zero per-layer stats SgAll[6][1024]
// ---------------------------------------------------------------------------
__global__ __launch_bounds__(256) void setup_kernel(
    const float* __restrict__ Wq, const float* __restrict__ Wk,
    const float* __restrict__ Wv, const float* __restrict__ Wm,
    const float* __restrict__ W1, const float* __restrict__ W2,
    const float* __restrict__ bmv, const float* __restrict__ b1,
    const float* __restrict__ bq, const float* __restrict__ bk,
    const float* __restrict__ bv,
    const float* __restrict__ desc0, const float* __restrict__ desc1,
    unsigned short* __restrict__ Wqkv, unsigned short* __restrict__ Wb2,
    unsigned short* __restrict__ Wmix, float* __restrict__ b1m,
    unsigned short* __restrict__ dT0, unsigned short* __restrict__ dT1,
    float* __restrict__ o0, float* __restrict__ o1,
    unsigned short* __restrict__ Qb0, unsigned short* __restrict__ Qb1,
    unsigned short* __restrict__ Kt0, unsigned short* __restrict__ Kt1,
    unsigned short* __restrict__ Vb0, unsigned short* __restrict__ Vb1,
    float* __restrict__ SgAll) {
  __shared__ __align__(16) unsigned char ARENA[17408];
  const int bid = blockIdx.x;
  const int t = threadIdx.x;

  if (bid < 672) {
    int idx = (bid * 256 + t) * 4;
    if (idx >= 688128) return;
    const float* src; unsigned short* dst; int soff, doff;
    if (idx < 98304)       { src = Wq; soff = idx; dst = Wqkv; doff = idx; }
    else if (idx < 196608) { src = Wk; soff = idx - 98304; dst = Wqkv; doff = idx; }
    else if (idx < 294912) { src = Wv; soff = idx - 196608; dst = Wqkv; doff = idx; }
    else if (idx < 491520) { src = W2; soff = idx - 294912; dst = Wb2; doff = soff; }
    else {
      int f = idx - 491520;
      int l = f >> 15, rem = f & 32767;
      int i = rem >> 7, c = rem & 127;
      src = W1; soff = (l << 16) + (i << 8) + c;
      dst = Wmix; doff = (l << 16) + (i << 8) + c;
    }
    float4 v = *(const float4*)&src[soff];
    uint2 p = { pk2(v.x, v.y), pk2(v.z, v.w) };
    *(uint2*)&dst[doff] = p;
  } else if (bid < 720) {
    const int b = bid - 672;
    const int jb = b & 1, ib = (b >> 1) & 3, l = b >> 3;
    const int bj = jb * 64, bi = ib * 64;
    float* Ws = (float*)ARENA;            // [32][65]
    float* Xs = (float*)ARENA + 2080;     // [32][64]
    const int ti = (t >> 4) << 2;
    const int tj = (t & 15) << 2;
    float acc[4][4] = {{0.f}};
    for (int k0 = 0; k0 < 128; k0 += 32) {
#pragma unroll
      for (int i = 0; i < 8; ++i) {
        int e = t + i * 256;
        int ii = e >> 5, kk = e & 31;
        Ws[kk * 65 + ii] = W1[(size_t)(l << 16) + (bi + ii) * 256 + 128 + k0 + kk];
      }
#pragma unroll
      for (int i = 0; i < 2; ++i) {
        int e = t + i * 256;
        int r = e >> 4, c4 = e & 15;
        *(float4*)&Xs[r * 64 + c4 * 4] =
            *(const float4*)&Wm[(size_t)l * 16384 + (k0 + r) * 128 + bj + c4 * 4];
      }
      __syncthreads();
#pragma unroll
      for (int kk = 0; kk < 32; ++kk) {
        float a[4];
        a[0] = Ws[kk * 65 + ti]; a[1] = Ws[kk * 65 + ti + 1];
        a[2] = Ws[kk * 65 + ti + 2]; a[3] = Ws[kk * 65 + ti + 3];
        float4 b4 = *(const float4*)&Xs[kk * 64 + tj];
        float bb[4] = {b4.x, b4.y, b4.z, b4.w};
#pragma unroll
        for (int i = 0; i < 4; ++i)
#pragma unroll
          for (int j = 0; j < 4; ++j) acc[i][j] += a[i] * bb[j];
      }
      __syncthreads();
    }
#pragma unroll
    for (int i = 0; i < 4; ++i) {
      uint2 p = { pk2(acc[i][0], acc[i][1]), pk2(acc[i][2], acc[i][3]) };
      *(uint2*)&Wmix[(size_t)(l << 16) + (bi + ti + i) * 256 + 128 + bj + tj] = p;
    }
    if (jb == 0 && ib == 0) {
      float a = b1[l * 256 + t];
      const float* wr = &W1[(size_t)(l << 16) + t * 256 + 128];
      const float* bp = &bmv[l * 128];
      for (int k = 0; k < 128; k += 4)
        a += wr[k] * bp[k] + wr[k + 1] * bp[k + 1] + wr[k + 2] * bp[k + 2] + wr[k + 3] * bp[k + 3];
      b1m[l * 256 + t] = a;
    }
  } else if (bid < 784) {
    const int b = bid - 720;
    const int dsc = b >> 5;
    const float* D = dsc ? desc1 : desc0;
    unsigned short* T = dsc ? dT1 : dT0;
    float* O = dsc ? o1 : o0;
    const int n0 = (b & 31) * 64;
    unsigned short* L = (unsigned short*)ARENA;   // [64][136]
#pragma unroll
    for (int i = 0; i < 8; ++i) {
      int idx = t + i * 256;
      int c = idx >> 4, nj = (idx & 15) * 4;
      float4 v = *(const float4*)&D[(size_t)c * NN + n0 + nj];
      *(float4*)&O[(size_t)c * NN + n0 + nj] = v;
      L[(nj + 0) * 136 + c] = (unsigned short)f2bf(v.x);
      L[(nj + 1) * 136 + c] = (unsigned short)f2bf(v.y);
      L[(nj + 2) * 136 + c] = (unsigned short)f2bf(v.z);
      L[(nj + 3) * 136 + c] = (unsigned short)f2bf(v.w);
    }
    __syncthreads();
#pragma unroll
    for (int i = 0; i < 4; ++i) {
      int idx = t + i * 256;
      int n = idx >> 4, cj = (idx & 15) * 8;
      uint4 v = *(const uint4*)&L[n * 136 + cj];
      *(uint4*)&T[(size_t)(n0 + n) * 128 + cj] = v;
    }
    // ---- layer-0 QKV for queries n0..n0+63 straight from LDS ----
    const int wid = t >> 6, lane = t & 63;
    const int col = lane & 15, Qd = lane >> 4;
    const int nl = wid * 16 + col;
    const int n = n0 + nl;
    unsigned short* Qb = dsc ? Qb1 : Qb0;
    unsigned short* Kt = dsc ? Kt1 : Kt0;
    unsigned short* Vb = dsc ? Vb1 : Vb0;
#pragma unroll
    for (int op = 0; op < 3; ++op) {
      const float* W = (op == 0) ? Wq : (op == 1) ? Wk : Wv;
      const float* bias = (op == 0) ? bq : (op == 1) ? bk : bv;
      f32x4 acc[8];
#pragma unroll
      for (int mt = 0; mt < 8; ++mt) acc[mt] = (f32x4){0.f, 0.f, 0.f, 0.f};
#pragma unroll
      for (int k0 = 0; k0 < 128; k0 += 32) {
        union { uint4 q; bf16x8 v; } bfr;
        bfr.q = *(const uint4*)&L[nl * 136 + k0 + Qd * 8];
#pragma unroll
        for (int mt = 0; mt < 8; ++mt) {
          const float* wp = &W[(size_t)(mt * 16 + col) * 128 + k0 + Qd * 8];
          float4 a0 = *(const float4*)wp;
          float4 a1 = *(const float4*)(wp + 4);
          union { unsigned int u[4]; bf16x8 v; } af;
          af.u[0] = pk2(a0.x, a0.y); af.u[1] = pk2(a0.z, a0.w);
          af.u[2] = pk2(a1.x, a1.y); af.u[3] = pk2(a1.z, a1.w);
          acc[mt] = __builtin_amdgcn_mfma_f32_16x16x32_bf16(af.v, bfr.v, acc[mt], 0, 0, 0);
        }
      }
#pragma unroll
      for (int mt = 0; mt < 8; ++mt) {
        const int c0 = mt * 16 + Qd * 4;
        float v0 = acc[mt][0] + bias[c0], v1 = acc[mt][1] + bias[c0 + 1];
        float v2 = acc[mt][2] + bias[c0 + 2], v3 = acc[mt][3] + bias[c0 + 3];
        const int d = c0 >> 2;
        if (op == 0) {
          const float sc = 0.25503488f;  // 1/sqrt(32)*log2e
          v0 *= sc; v1 *= sc; v2 *= sc; v3 *= sc;
          Qb[(size_t)(0 * 32 + d) * NN + n] = (unsigned short)f2bf(v0);
          Qb[(size_t)(1 * 32 + d) * NN + n] = (unsigned short)f2bf(v1);
          Qb[(size_t)(2 * 32 + d) * NN + n] = (unsigned short)f2bf(v2);
          Qb[(size_t)(3 * 32 + d) * NN + n] = (unsigned short)f2bf(v3);
        } else if (op == 1) {
          Kt[((size_t)0 * NN + n) * 32 + d] = (unsigned short)f2bf(v0);
          Kt[((size_t)1 * NN + n) * 32 + d] = (unsigned short)f2bf(v1);
          Kt[((size_t)2 * NN + n) * 32 + d] = (unsigned short)f2bf(v2);
          Kt[((size_t)3 * NN + n) * 32 + d] = (unsigned short)f2bf(v3);
        } else {
          Vb[(size_t)(0 * 32 + d) * NN + n] = (unsigned short)f2bf(v0);
          Vb[(size_t)(1 * 32 + d) * NN + n] = (unsigned short)f2bf(v1);
          Vb[(size_t)(2 * 32 + d) * NN + n] = (unsigned short)f2bf(v2);
          Vb[(size_t)(3 * 32 + d) * NN + n] = (unsigned short)f2bf(v3);
        }
      }
    }
  } else {
    const int b = bid - 784;   // layer index
    float4 z = make_float4(0.f, 0.f, 0.f, 0.f);
    *(float4*)&SgAll[b * 1024 + t * 4] = z;
  }
}

// ---------------------------------------------------------------------------
// Direct-fragment bf16 MFMA GEMM (R11). Tile 64M x 64N, 4 waves.
// Modes: 4=mlp2 (norm+relu B, fp32 residual += Cf, bf16 Cb)
//        5=mlp1 (bf16 out_T [n][ldc] + per-channel sum/ssq atomics into Cf)
// ---------------------------------------------------------------------------
struct MOp {
  const unsigned short* A;
  const float* bias;
  const unsigned short* B1;
  const unsigned short* B2;
  unsigned short* Cb;
  float* Cf;
  const float* Sp;
  int ldb, ldc, mode;
};
struct MOps8 { MOp op[8]; };

template <int K>
__global__ __launch_bounds__(256) void gemm_direct_kernel(MOps8 P) {
  const MOp g = P.op[blockIdx.z];
  const int t = threadIdx.x;
  const int w = t >> 6, lane = t & 63;
  const int col = lane & 15, Qd = lane >> 4;
  const int bm = blockIdx.y * 64;
  const int bn = blockIdx.x * 64;

  __shared__ float meanL[256], rstdL[256];
  __shared__ float swS[4][64], swQ[4][64];

  if (g.mode == 4) {
    float s = g.Sp[t * 2], ss = g.Sp[t * 2 + 1];
    float mean = s * (1.0f / NN);
    float var = fmaxf(ss * (1.0f / NN) - mean * mean, 0.f);
    meanL[t] = mean;
    rstdL[t] = rsqrtf(var + 1e-5f);
  }
  __syncthreads();

  const int n = bn + w * 16 + col;
  f32x4 acc[4];
#pragma unroll
  for (int mt = 0; mt < 4; ++mt) acc[mt] = (f32x4){0.f, 0.f, 0.f, 0.f};

#pragma unroll
  for (int k0 = 0; k0 < K; k0 += 32) {
    bf16x8 af[4];
#pragma unroll
    for (int mt = 0; mt < 4; ++mt)
      af[mt] = *(const bf16x8*)&g.A[(size_t)(bm + mt * 16 + col) * K + k0 + Qd * 8];
    const unsigned short* Bp = g.B1;
    int kk = k0;
    if (g.B2 && k0 >= 128) { Bp = g.B2; kk = k0 - 128; }
    uint4 v = *(const uint4*)&Bp[(size_t)n * g.ldb + kk + Qd * 8];
    if (g.mode == 4) {
      float4 mA = *(const float4*)&meanL[k0 + Qd * 8];
      float4 mB = *(const float4*)&meanL[k0 + Qd * 8 + 4];
      float4 rA = *(const float4*)&rstdL[k0 + Qd * 8];
      float4 rB = *(const float4*)&rstdL[k0 + Qd * 8 + 4];
      union { uint4 q; unsigned short us[8]; } u;
      u.q = v;
      float x0 = fmaxf((bf2f(u.us[0]) - mA.x) * rA.x, 0.f);
      float x1 = fmaxf((bf2f(u.us[1]) - mA.y) * rA.y, 0.f);
      float x2 = fmaxf((bf2f(u.us[2]) - mA.z) * rA.z, 0.f);
      float x3 = fmaxf((bf2f(u.us[3]) - mA.w) * rA.w, 0.f);
      float x4 = fmaxf((bf2f(u.us[4]) - mB.x) * rB.x, 0.f);
      float x5 = fmaxf((bf2f(u.us[5]) - mB.y) * rB.y, 0.f);
      float x6 = fmaxf((bf2f(u.us[6]) - mB.z) * rB.z, 0.f);
      float x7 = fmaxf((bf2f(u.us[7]) - mB.w) * rB.w, 0.f);
      u.q.x = pk2(x0, x1); u.q.y = pk2(x2, x3);
      u.q.z = pk2(x4, x5); u.q.w = pk2(x6, x7);
      v = u.q;
    }
    union { uint4 q; bf16x8 b; } bc;
    bc.q = v;
#pragma unroll
    for (int mt = 0; mt < 4; ++mt)
      acc[mt] = __builtin_amdgcn_mfma_f32_16x16x32_bf16(af[mt], bc.b, acc[mt], 0, 0, 0);
  }

#pragma unroll
  for (int mt = 0; mt < 4; ++mt) {
    const int c0 = bm + mt * 16 + Qd * 4;
    const float b0 = g.bias[c0], b1 = g.bias[c0 + 1];
    const float b2 = g.bias[c0 + 2], b3 = g.bias[c0 + 3];
    f32x4 a = acc[mt];
    float v0 = a[0] + b0, v1 = a[1] + b1, v2 = a[2] + b2, v3 = a[3] + b3;
    if (g.mode == 5) {
      uint2 pv = { pk2(v0, v1), pk2(v2, v3) };
      *(uint2*)&g.Cb[(size_t)n * g.ldc + c0] = pv;
      float sA[4] = {v0, v1, v2, v3};
      float sQ[4] = {v0 * v0, v1 * v1, v2 * v2, v3 * v3};
#pragma unroll
      for (int r = 0; r < 4; ++r) {
#pragma unroll
        for (int off = 1; off < 16; off <<= 1) {
          sA[r] += __shfl_xor(sA[r], off);
          sQ[r] += __shfl_xor(sQ[r], off);
        }
      }
      if (col == 0) {
#pragma unroll
        for (int r = 0; r < 4; ++r) {
          swS[w][mt * 16 + Qd * 4 + r] = sA[r];
          swQ[w][mt * 16 + Qd * 4 + r] = sQ[r];
        }
      }
    } else {  // mode 4
      float* dp = g.Cf;
      float o0 = dp[(size_t)(c0 + 0) * NN + n] + v0;
      float o1 = dp[(size_t)(c0 + 1) * NN + n] + v1;
      float o2 = dp[(size_t)(c0 + 2) * NN + n] + v2;
      float o3 = dp[(size_t)(c0 + 3) * NN + n] + v3;
      dp[(size_t)(c0 + 0) * NN + n] = o0;
      dp[(size_t)(c0 + 1) * NN + n] = o1;
      dp[(size_t)(c0 + 2) * NN + n] = o2;
      dp[(size_t)(c0 + 3) * NN + n] = o3;
      uint2 pv = { pk2(o0, o1), pk2(o2, o3) };
      *(uint2*)&g.Cb[(size_t)n * g.ldc + c0] = pv;
    }
  }
  if (g.mode == 5) {
    __syncthreads();
    if (t < 64) {
      float a = swS[0][t] + swS[1][t] + swS[2][t] + swS[3][t];
      float b = swQ[0][t] + swQ[1][t] + swQ[2][t] + swQ[3][t];
      atomicAdd(&g.Cf[(bm + t) * 2], a);
      atomicAdd(&g.Cf[(bm + t) * 2 + 1], b);
    }
  }
}

// ---------------------------------------------------------------------------
// MFMA flash attention (R11/R9): single-pass online softmax, direct-fragment
// K/V loads, wave-private key quarters, barrier-free loop.
// Grid: (128 q-tiles of 16, 8 = desc*4+head). Block 256 = 4 waves.
// ---------------------------------------------------------------------------
__global__ __launch_bounds__(256, 4) void attn_mfma_kernel(
    const unsigned short* __restrict__ Qb0, const unsigned short* __restrict__ Kt0,
    const unsigned short* __restrict__ Vb0, const unsigned short* __restrict__ Qb1,
    const unsigned short* __restrict__ Kt1, const unsigned short* __restrict__ Vb1,
    unsigned short* __restrict__ mgT0, unsigned short* __restrict__ mgT1, int cross) {
  const int z = blockIdx.y, desc = z >> 2, h = z & 3;
  const int t = threadIdx.x;
  const int wid = t >> 6, lane = t & 63;
  const int col = lane & 15, Qd = lane >> 4;
  const int qb = blockIdx.x * 16;

  const unsigned short* Qb = desc ? Qb1 : Qb0;
  const int s = cross ? (1 - desc) : desc;
  const unsigned short* Kt = s ? Kt1 : Kt0;
  const unsigned short* Vb = s ? Vb1 : Vb0;

  __shared__ __align__(16) unsigned short SM[7424];
  unsigned short* PW = SM + wid * 640;
  float* fS = (float*)(SM + 2560);

  bf16x8 bq;
  {
    union { unsigned short u[8]; bf16x8 v; } tmp;
#pragma unroll
    for (int j = 0; j < 8; ++j)
      tmp.u[j] = Qb[(size_t)(h * 32 + Qd * 8 + j) * NN + qb + col];
    bq = tmp.v;
  }

  f32x4 o0 = {0.f, 0.f, 0.f, 0.f}, o1 = {0.f, 0.f, 0.f, 0.f};
  float m = -1e30f, l = 0.f;

  const int kq = wid * 512;
#pragma unroll 2
  for (int it = 0; it < 16; ++it) {
    const int k0 = kq + it * 32;
    bf16x8 aK0 = *(const bf16x8*)&Kt[((size_t)h * NN + k0 + col) * 32 + Qd * 8];
    bf16x8 aK1 = *(const bf16x8*)&Kt[((size_t)h * NN + k0 + 16 + col) * 32 + Qd * 8];
    bf16x8 av0 = *(const bf16x8*)&Vb[(size_t)(h * 32 + col) * NN + k0 + Qd * 8];
    bf16x8 av1 = *(const bf16x8*)&Vb[(size_t)(h * 32 + 16 + col) * NN + k0 + Qd * 8];
    f32x4 z4 = {0.f, 0.f, 0.f, 0.f};
    f32x4 s0 = __builtin_amdgcn_mfma_f32_16x16x32_bf16(aK0, bq, z4, 0, 0, 0);
    f32x4 s1 = __builtin_amdgcn_mfma_f32_16x16x32_bf16(aK1, bq, z4, 0, 0, 0);
    float cm = fmaxf(fmaxf(fmaxf(s0[0], s0[1]), fmaxf(s0[2], s0[3])),
                     fmaxf(fmaxf(s1[0], s1[1]), fmaxf(s1[2], s1[3])));
    cm = fmaxf(cm, __shfl_xor(cm, 16));
    cm = fmaxf(cm, __shfl_xor(cm, 32));
    const float mn = fmaxf(m, cm);
    const float alpha = exp2f(m - mn);
    m = mn;
    float p00 = exp2f(s0[0] - mn), p01 = exp2f(s0[1] - mn);
    float p02 = exp2f(s0[2] - mn), p03 = exp2f(s0[3] - mn);
    float p10 = exp2f(s1[0] - mn), p11 = exp2f(s1[1] - mn);
    float p12 = exp2f(s1[2] - mn), p13 = exp2f(s1[3] - mn);
    float us = (p00 + p01) + (p02 + p03) + (p10 + p11) + (p12 + p13);
    us += __shfl_xor(us, 16);
    us += __shfl_xor(us, 32);
    l = l * alpha + us;
    uint2 w0 = { pk2(p00, p01), pk2(p02, p03) };
    uint2 w1 = { pk2(p10, p11), pk2(p12, p13) };
    *(uint2*)&PW[col * 40 + Qd * 4] = w0;
    *(uint2*)&PW[col * 40 + 16 + Qd * 4] = w1;
    bf16x8 pb = *(const bf16x8*)&PW[col * 40 + Qd * 8];
    o0 = o0 * alpha;
    o1 = o1 * alpha;
    o0 = __builtin_amdgcn_mfma_f32_16x16x32_bf16(av0, pb, o0, 0, 0, 0);
    o1 = __builtin_amdgcn_mfma_f32_16x16x32_bf16(av1, pb, o1, 0, 0, 0);
  }

  __syncthreads();
  *(float4*)&fS[wid * 576 + col * 36 + Qd * 4] =
      make_float4(o0[0], o0[1], o0[2], o0[3]);
  *(float4*)&fS[wid * 576 + col * 36 + 16 + Qd * 4] =
      make_float4(o1[0], o1[1], o1[2], o1[3]);
  if (Qd == 0) {
    fS[2304 + wid * 16 + col] = m;
    fS[2368 + wid * 16 + col] = l;
  }
  __syncthreads();
  {
    const int q16 = t >> 4, dg = t & 15;
    float m0 = fS[2304 + q16], m1 = fS[2304 + 16 + q16];
    float m2 = fS[2304 + 32 + q16], m3 = fS[2304 + 48 + q16];
    float M = fmaxf(fmaxf(m0, m1), fmaxf(m2, m3));
    float w0 = exp2f(m0 - M), w1 = exp2f(m1 - M);
    float w2 = exp2f(m2 - M), w3 = exp2f(m3 - M);
    float L = w0 * fS[2368 + q16] + w1 * fS[2368 + 16 + q16] +
              w2 * fS[2368 + 32 + q16] + w3 * fS[2368 + 48 + q16];
    float inv = 1.0f / L;
    unsigned short* T = desc ? mgT1 : mgT0;
    const int q = qb + q16;
#pragma unroll
    for (int r = 0; r < 2; ++r) {
      int d = dg * 2 + r;
      float v = (w0 * fS[0 * 576 + q16 * 36 + d] + w1 * fS[1 * 576 + q16 * 36 + d] +
                 w2 * fS[2 * 576 + q16 * 36 + d] + w3 * fS[3 * 576 + q16 * 36 + d]) * inv;
      T[(size_t)q * 128 + d * 4 + h] = (unsigned short)f2bf(v);
    }
  }
}

// ---------------------------------------------------------------------------
// Fused tail: mlp2(layer l) + QKV(layer l+1) (unchanged from R11).
// ---------------------------------------------------------------------------
struct FDesc {
  const unsigned short* HT; const float* Sp; float* outF; unsigned short* dT;
  unsigned short* Qb; unsigned short* Kt; unsigned short* Vb;
};
struct FArgs {
  FDesc d[2];
  const unsigned short *W2l, *Wql, *Wkl, *Wvl;
  const float *b2l, *bql, *bkl, *bvl;
};

__global__ __launch_bounds__(256) void fused_tail_kernel(FArgs F) {
  const FDesc g = F.d[blockIdx.y];
  const int t = threadIdx.x;
  const int w = t >> 6, lane = t & 63;
  const int col = lane & 15, Qd = lane >> 4;
  const int nb = blockIdx.x * 16;
  const int n = nb + col;

  __shared__ float meanL[256], rstdL[256];
  __shared__ __align__(16) unsigned short dTs[16 * 136];

  {
    float s = g.Sp[t * 2], ss = g.Sp[t * 2 + 1];
    float mean = s * (1.0f / NN);
    float var = fmaxf(ss * (1.0f / NN) - mean * mean, 0.f);
    meanL[t] = mean;
    rstdL[t] = rsqrtf(var + 1e-5f);
  }
  __syncthreads();

  f32x4 accA[2];
  accA[0] = (f32x4){0.f, 0.f, 0.f, 0.f};
  accA[1] = (f32x4){0.f, 0.f, 0.f, 0.f};
#pragma unroll
  for (int k0 = 0; k0 < 256; k0 += 32) {
    uint4 v = *(const uint4*)&g.HT[(size_t)n * 256 + k0 + Qd * 8];
    float4 mA = *(const float4*)&meanL[k0 + Qd * 8];
    float4 mB = *(const float4*)&meanL[k0 + Qd * 8 + 4];
    float4 rA = *(const float4*)&rstdL[k0 + Qd * 8];
    float4 rB = *(const float4*)&rstdL[k0 + Qd * 8 + 4];
    union { uint4 q; unsigned short us[8]; } u;
    u.q = v;
    float x0 = fmaxf((bf2f(u.us[0]) - mA.x) * rA.x, 0.f);
    float x1 = fmaxf((bf2f(u.us[1]) - mA.y) * rA.y, 0.f);
    float x2 = fmaxf((bf2f(u.us[2]) - mA.z) * rA.z, 0.f);
    float x3 = fmaxf((bf2f(u.us[3]) - mA.w) * rA.w, 0.f);
    float x4 = fmaxf((bf2f(u.us[4]) - mB.x) * rB.x, 0.f);
    float x5 = fmaxf((bf2f(u.us[5]) - mB.y) * rB.y, 0.f);
    float x6 = fmaxf((bf2f(u.us[6]) - mB.z) * rB.z, 0.f);
    float x7 = fmaxf((bf2f(u.us[7]) - mB.w) * rB.w, 0.f);
    u.q.x = pk2(x0, x1); u.q.y = pk2(x2, x3);
    u.q.z = pk2(x4, x5); u.q.w = pk2(x6, x7);
    union { uint4 q; bf16x8 b; } bc;
    bc.q = u.q;
#pragma unroll
    for (int mt = 0; mt < 2; ++mt) {
      bf16x8 af = *(const bf16x8*)&F.W2l[(size_t)(w * 32 + mt * 16 + col) * 256 + k0 + Qd * 8];
      accA[mt] = __builtin_amdgcn_mfma_f32_16x16x32_bf16(af, bc.b, accA[mt], 0, 0, 0);
    }
  }
#pragma unroll
  for (int mt = 0; mt < 2; ++mt) {
    const int c0 = w * 32 + mt * 16 + Qd * 4;
    f32x4 a = accA[mt];
    float o0 = g.outF[(size_t)(c0 + 0) * NN + n] + a[0] + F.b2l[c0 + 0];
    float o1 = g.outF[(size_t)(c0 + 1) * NN + n] + a[1] + F.b2l[c0 + 1];
    float o2 = g.outF[(size_t)(c0 + 2) * NN + n] + a[2] + F.b2l[c0 + 2];
    float o3 = g.outF[(size_t)(c0 + 3) * NN + n] + a[3] + F.b2l[c0 + 3];
    g.outF[(size_t)(c0 + 0) * NN + n] = o0;
    g.outF[(size_t)(c0 + 1) * NN + n] = o1;
    g.outF[(size_t)(c0 + 2) * NN + n] = o2;
    g.outF[(size_t)(c0 + 3) * NN + n] = o3;
    unsigned short s0 = (unsigned short)f2bf(o0), s1 = (unsigned short)f2bf(o1);
    unsigned short s2 = (unsigned short)f2bf(o2), s3 = (unsigned short)f2bf(o3);
    dTs[col * 136 + c0 + 0] = s0;
    dTs[col * 136 + c0 + 1] = s1;
    dTs[col * 136 + c0 + 2] = s2;
    dTs[col * 136 + c0 + 3] = s3;
    uint2 pv = { ((unsigned int)s0) | (((unsigned int)s1) << 16),
                 ((unsigned int)s2) | (((unsigned int)s3) << 16) };
    *(uint2*)&g.dT[(size_t)n * 128 + c0] = pv;
  }
  __syncthreads();

  f32x4 accB[6];
#pragma unroll
  for (int f = 0; f < 6; ++f) accB[f] = (f32x4){0.f, 0.f, 0.f, 0.f};
#pragma unroll
  for (int k0 = 0; k0 < 128; k0 += 32) {
    bf16x8 bq = *(const bf16x8*)&dTs[col * 136 + k0 + Qd * 8];
#pragma unroll
    for (int f = 0; f < 6; ++f) {
      const int idx = w * 6 + f;
      const int op = idx >> 3, mt = idx & 7;
      const unsigned short* W = (op == 0) ? F.Wql : (op == 1) ? F.Wkl : F.Wvl;
      bf16x8 af = *(const bf16x8*)&W[(size_t)(mt * 16 + col) * 128 + k0 + Qd * 8];
      accB[f] = __builtin_amdgcn_mfma_f32_16x16x32_bf16(af, bq, accB[f], 0, 0, 0);
    }
  }
#pragma unroll
  for (int f = 0; f < 6; ++f) {
    const int idx = w * 6 + f;
    const int op = idx >> 3, mt = idx & 7;
    const float* bias = (op == 0) ? F.bql : (op == 1) ? F.bkl : F.bvl;
    const int c0 = mt * 16 + Qd * 4;
    f32x4 a = accB[f];
    float v0 = a[0] + bias[c0], v1 = a[1] + bias[c0 + 1];
    float v2 = a[2] + bias[c0 + 2], v3 = a[3] + bias[c0 + 3];
    const int d = c0 >> 2;
    if (op == 0) {
      const float sc = 0.25503488f;  // 1/sqrt(32)*log2e
      v0 *= sc; v1 *= sc; v2 *= sc; v3 *= sc;
      g.Qb[(size_t)(0 * 32 + d) * NN + n] = (unsigned short)f2bf(v0);
      g.Qb[(size_t)(1 * 32 + d) * NN + n] = (unsigned short)f2bf(v1);
      g.Qb[(size_t)(2 * 32 + d) * NN + n] = (unsigned short)f2bf(v2);
      g.Qb[(size_t)(3 * 32 + d) * NN + n] = (unsigned short)f2bf(v3);
    } else if (op == 1) {
      g.Kt[((size_t)0 * NN + n) * 32 + d] = (unsigned short)f2bf(v0);
      g.Kt[((size_t)1 * NN + n) * 32 + d] = (unsigned short)f2bf(v1);
      g.Kt[((size_t)2 * NN + n) * 32 + d] = (unsigned short)f2bf(v2);
      g.Kt[((size_t)3 * NN + n) * 32 + d] = (unsigned short)f2bf(v3);
    } else {
      g.Vb[(size_t)(0 * 32 + d) * NN + n] = (unsigned short)f2bf(v0);
      g.Vb[(size_t)(1 * 32 + d) * NN + n] = (unsigned short)f2bf(v1);
      g.Vb[(size_t)(2 * 32 + d) * NN + n] = (unsigned short)f2bf(v2);
      g.Vb[(size_t)(3 * 32 + d) * NN + n] = (unsigned short)f2bf(v3);
    }
  }
}

// ---------------------------------------------------------------------------
extern "C" void kernel_launch(void* const* d_in, const int* in_sizes, int n_in,
                              void* d_out, int out_size, void* d_ws, size_t ws_size,
                              hipStream_t stream) {
  const float* desc0 = (const float*)d_in[0];
  const float* desc1 = (const float*)d_in[1];
  const float* Wq = (const float*)d_in[2];
  const float* bq = (const float*)d_in[3];
  const float* Wk = (const float*)d_in[4];
  const float* bk = (const float*)d_in[5];
  const float* Wv = (const float*)d_in[6];
  const float* bv = (const float*)d_in[7];
  const float* Wm = (const float*)d_in[8];
  const float* bmv = (const float*)d_in[9];
  const float* W1 = (const float*)d_in[10];
  const float* b1 = (const float*)d_in[11];
  const float* W2 = (const float*)d_in[12];
  const float* b2 = (const float*)d_in[13];

  float* out0 = (float*)d_out;
  float* out1 = out0 + (size_t)DDIM * NN;

  float* fws = (float*)d_ws;
  float* SgAll = fws;                  // 6 x 1024
  float* b1m = SgAll + 6144;           // 1536
  unsigned short* uws = (unsigned short*)(b1m + 1536);
  unsigned short* dT0 = uws;                     // 262144 each
  unsigned short* dT1 = uws + 1 * 262144;
  unsigned short* Qb0 = uws + 2 * 262144;
  unsigned short* Qb1 = uws + 3 * 262144;
  unsigned short* Kt0 = uws + 4 * 262144;
  unsigned short* Kt1 = uws + 5 * 262144;
  unsigned short* Vb0 = uws + 6 * 262144;
  unsigned short* Vb1 = uws + 7 * 262144;
  unsigned short* mgT0 = uws + 8 * 262144;
  unsigned short* mgT1 = uws + 9 * 262144;
  unsigned short* HT0 = uws + 10 * 262144;       // 524288
  unsigned short* HT1 = HT0 + 524288;            // 524288
  unsigned short* Wqkv = HT1 + 524288;           // 294912
  unsigned short* Wb2 = Wqkv + 294912;           // 196608
  unsigned short* Wmix = Wb2 + 196608;           // 393216

  setup_kernel<<<790, 256, 0, stream>>>(Wq, Wk, Wv, Wm, W1, W2, bmv, b1,
                                        bq, bk, bv, desc0, desc1,
                                        Wqkv, Wb2, Wmix, b1m, dT0, dT1,
                                        out0, out1, Qb0, Qb1, Kt0, Kt1,
                                        Vb0, Vb1, SgAll);

  for (int l = 0; l < NL; ++l) {
    const unsigned short* w2 = Wb2 + l * 32768;
    const float* b2p = b2 + (size_t)l * 128;
    float* Sg0 = SgAll + l * 1024;
    float* Sg1 = Sg0 + 512;

    attn_mfma_kernel<<<dim3(128, 8), 256, 0, stream>>>(
        Qb0, Kt0, Vb0, Qb1, Kt1, Vb1, mgT0, mgT1, l & 1);

    MOps8 P1 = {};
    P1.op[0] = {Wmix + l * 65536, b1m + (size_t)l * 256, dT0, mgT0, HT0, Sg0, nullptr, 128, 256, 5};
    P1.op[1] = {Wmix + l * 65536, b1m + (size_t)l * 256, dT1, mgT1, HT1, Sg1, nullptr, 128, 256, 5};
    gemm_direct_kernel<256><<<dim3(32, 4, 2), 256, 0, stream>>>(P1);

    if (l < NL - 1) {
      FArgs F;
      F.d[0] = {HT0, Sg0, out0, dT0, Qb0, Kt0, Vb0};
      F.d[1] = {HT1, Sg1, out1, dT1, Qb1, Kt1, Vb1};
      F.W2l = w2;
      F.Wql = Wqkv + (l + 1) * 16384;
      F.Wkl = Wqkv + 98304 + (l + 1) * 16384;
      F.Wvl = Wqkv + 196608 + (l + 1) * 16384;
      F.b2l = b2p;
      F.bql = bq + (size_t)(l + 1) * 128;
      F.bkl = bk + (size_t)(l + 1) * 128;
      F.bvl = bv + (size_t)(l + 1) * 128;
      fused_tail_kernel<<<dim3(128, 2), 256, 0, stream>>>(F);
    } else {
      MOps8 P2 = {};
      P2.op[0] = {w2, b2p, HT0, nullptr, dT0, out0, Sg0, 256, 128, 4};
      P2.op[1] = {w2, b2p, HT1, nullptr, dT1, out1, Sg1, 256, 128, 4};
      gemm_direct_kernel<256><<<dim3(32, 2, 2), 256, 0, stream>>>(P2);
    }
  }
}

// Round 14
// 402.497 us; speedup vs baseline: 2.9897x; 1.0505x over previous
//
#include <hip/hip_runtime.h>

#define NN 2048
#define DDIM 128
#define NHEAD 4
#define DH 32
#define NL 6

typedef __attribute__((ext_vector_type(8))) __bf16 bf16x8;
typedef __attribute__((ext_vector_type(4))) float f32x4;

__device__ __forceinline__ unsigned int f2bf(float x) {
  unsigned int u = __float_as_uint(x);
  u += 0x7fff + ((u >> 16) & 1);   // RNE
  return u >> 16;
}
__device__ __forceinline__ unsigned int pk2(float a, float b) {
  return f2bf(a) | (f2bf(b) << 16);
}
__device__ __forceinline__ float bf2f(unsigned short u) {
  return __uint_as_float(((unsigned int)u) << 16);
}

// ---------------------------------------------------------------------------
// Fused setup: 790 blocks.
//   0..671  : weight cast fp32->bf16 (Wqkv | Wb2 | Wmix low-k)
//   672..719: Wmix high-k = W1b @ Wm + b1 fold
//   720..783: desc transpose/cast + fp32 residual copy
//   784..789: zero per-layer stats SgAll[6][1024]
// ---------------------------------------------------------------------------
__global__ __launch_bounds__(256) void setup_kernel(
    const float* __restrict__ Wq, const float* __restrict__ Wk,
    const float* __restrict__ Wv, const float* __restrict__ Wm,
    const float* __restrict__ W1, const float* __restrict__ W2,
    const float* __restrict__ bmv, const float* __restrict__ b1,
    const float* __restrict__ desc0, const float* __restrict__ desc1,
    unsigned short* __restrict__ Wqkv, unsigned short* __restrict__ Wb2,
    unsigned short* __restrict__ Wmix, float* __restrict__ b1m,
    unsigned short* __restrict__ dT0, unsigned short* __restrict__ dT1,
    float* __restrict__ o0, float* __restrict__ o1,
    float* __restrict__ SgAll) {
  __shared__ __align__(16) unsigned char ARENA[17408];
  const int bid = blockIdx.x;
  const int t = threadIdx.x;

  if (bid < 672) {
    int idx = (bid * 256 + t) * 4;
    if (idx >= 688128) return;
    const float* src; unsigned short* dst; int soff, doff;
    if (idx < 98304)       { src = Wq; soff = idx; dst = Wqkv; doff = idx; }
    else if (idx < 196608) { src = Wk; soff = idx - 98304; dst = Wqkv; doff = idx; }
    else if (idx < 294912) { src = Wv; soff = idx - 196608; dst = Wqkv; doff = idx; }
    else if (idx < 491520) { src = W2; soff = idx - 294912; dst = Wb2; doff = soff; }
    else {
      int f = idx - 491520;
      int l = f >> 15, rem = f & 32767;
      int i = rem >> 7, c = rem & 127;
      src = W1; soff = (l << 16) + (i << 8) + c;
      dst = Wmix; doff = (l << 16) + (i << 8) + c;
    }
    float4 v = *(const float4*)&src[soff];
    uint2 p = { pk2(v.x, v.y), pk2(v.z, v.w) };
    *(uint2*)&dst[doff] = p;
  } else if (bid < 720) {
    const int b = bid - 672;
    const int jb = b & 1, ib = (b >> 1) & 3, l = b >> 3;
    const int bj = jb * 64, bi = ib * 64;
    float* Ws = (float*)ARENA;            // [32][65]
    float* Xs = (float*)ARENA + 2080;     // [32][64]
    const int ti = (t >> 4) << 2;
    const int tj = (t & 15) << 2;
    float acc[4][4] = {{0.f}};
    for (int k0 = 0; k0 < 128; k0 += 32) {
#pragma unroll
      for (int i = 0; i < 8; ++i) {
        int e = t + i * 256;
        int ii = e >> 5, kk = e & 31;
        Ws[kk * 65 + ii] = W1[(size_t)(l << 16) + (bi + ii) * 256 + 128 + k0 + kk];
      }
#pragma unroll
      for (int i = 0; i < 2; ++i) {
        int e = t + i * 256;
        int r = e >> 4, c4 = e & 15;
        *(float4*)&Xs[r * 64 + c4 * 4] =
            *(const float4*)&Wm[(size_t)l * 16384 + (k0 + r) * 128 + bj + c4 * 4];
      }
      __syncthreads();
#pragma unroll
      for (int kk = 0; kk < 32; ++kk) {
        float a[4];
        a[0] = Ws[kk * 65 + ti]; a[1] = Ws[kk * 65 + ti + 1];
        a[2] = Ws[kk * 65 + ti + 2]; a[3] = Ws[kk * 65 + ti + 3];
        float4 b4 = *(const float4*)&Xs[kk * 64 + tj];
        float bb[4] = {b4.x, b4.y, b4.z, b4.w};
#pragma unroll
        for (int i = 0; i < 4; ++i)
#pragma unroll
          for (int j = 0; j < 4; ++j) acc[i][j] += a[i] * bb[j];
      }
      __syncthreads();
    }
#pragma unroll
    for (int i = 0; i < 4; ++i) {
      uint2 p = { pk2(acc[i][0], acc[i][1]), pk2(acc[i][2], acc[i][3]) };
      *(uint2*)&Wmix[(size_t)(l << 16) + (bi + ti + i) * 256 + 128 + bj + tj] = p;
    }
    if (jb == 0 && ib == 0) {
      float a = b1[l * 256 + t];
      const float* wr = &W1[(size_t)(l << 16) + t * 256 + 128];
      const float* bp = &bmv[l * 128];
      for (int k = 0; k < 128; k += 4)
        a += wr[k] * bp[k] + wr[k + 1] * bp[k + 1] + wr[k + 2] * bp[k + 2] + wr[k + 3] * bp[k + 3];
      b1m[l * 256 + t] = a;
    }
  } else if (bid < 784) {
    const int b = bid - 720;
    const float* D = (b >> 5) ? desc1 : desc0;
    unsigned short* T = (b >> 5) ? dT1 : dT0;
    float* O = (b >> 5) ? o1 : o0;
    const int n0 = (b & 31) * 64;
    unsigned short* L = (unsigned short*)ARENA;   // [64][136]
#pragma unroll
    for (int i = 0; i < 8; ++i) {
      int idx = t + i * 256;
      int c = idx >> 4, nj = (idx & 15) * 4;
      float4 v = *(const float4*)&D[(size_t)c * NN + n0 + nj];
      *(float4*)&O[(size_t)c * NN + n0 + nj] = v;
      L[(nj + 0) * 136 + c] = (unsigned short)f2bf(v.x);
      L[(nj + 1) * 136 + c] = (unsigned short)f2bf(v.y);
      L[(nj + 2) * 136 + c] = (unsigned short)f2bf(v.z);
      L[(nj + 3) * 136 + c] = (unsigned short)f2bf(v.w);
    }
    __syncthreads();
#pragma unroll
    for (int i = 0; i < 4; ++i) {
      int idx = t + i * 256;
      int n = idx >> 4, cj = (idx & 15) * 8;
      uint4 v = *(const uint4*)&L[n * 136 + cj];
      *(uint4*)&T[(size_t)(n0 + n) * 128 + cj] = v;
    }
  } else {
    const int b = bid - 784;   // layer index
    float4 z = make_float4(0.f, 0.f, 0.f, 0.f);
    *(float4*)&SgAll[b * 1024 + t * 4] = z;
  }
}

// ---------------------------------------------------------------------------
// Direct-fragment bf16 MFMA GEMM. Tile 64M x 64N, 4 waves.
// Modes: 0=Q scaled  1=K transposed  2=V  4=mlp2(norm+relu B, residual)
//        5=mlp1 (bf16 out_T + per-channel sum/ssq atomics into Cf)
// ---------------------------------------------------------------------------
struct MOp {
  const unsigned short* A;
  const float* bias;
  const unsigned short* B1;
  const unsigned short* B2;
  unsigned short* Cb;
  float* Cf;
  const float* Sp;
  int ldb, ldc, mode;
};
struct MOps8 { MOp op[8]; };

template <int K>
__global__ __launch_bounds__(256) void gemm_direct_kernel(MOps8 P) {
  const MOp g = P.op[blockIdx.z];
  const int t = threadIdx.x;
  const int w = t >> 6, lane = t & 63;
  const int col = lane & 15, Qd = lane >> 4;
  const int bm = blockIdx.y * 64;
  const int bn = blockIdx.x * 64;

  __shared__ float meanL[256], rstdL[256];
  __shared__ float swS[4][64], swQ[4][64];

  if (g.mode == 4) {
    float s = g.Sp[t * 2], ss = g.Sp[t * 2 + 1];
    float mean = s * (1.0f / NN);
    float var = fmaxf(ss * (1.0f / NN) - mean * mean, 0.f);
    meanL[t] = mean;
    rstdL[t] = rsqrtf(var + 1e-5f);
  }
  __syncthreads();

  const int n = bn + w * 16 + col;
  f32x4 acc[4];
#pragma unroll
  for (int mt = 0; mt < 4; ++mt) acc[mt] = (f32x4){0.f, 0.f, 0.f, 0.f};

#pragma unroll
  for (int k0 = 0; k0 < K; k0 += 32) {
    bf16x8 af[4];
#pragma unroll
    for (int mt = 0; mt < 4; ++mt)
      af[mt] = *(const bf16x8*)&g.A[(size_t)(bm + mt * 16 + col) * K + k0 + Qd * 8];
    const unsigned short* Bp = g.B1;
    int kk = k0;
    if (g.B2 && k0 >= 128) { Bp = g.B2; kk = k0 - 128; }
    uint4 v = *(const uint4*)&Bp[(size_t)n * g.ldb + kk + Qd * 8];
    if (g.mode == 4) {
      float4 mA = *(const float4*)&meanL[k0 + Qd * 8];
      float4 mB = *(const float4*)&meanL[k0 + Qd * 8 + 4];
      float4 rA = *(const float4*)&rstdL[k0 + Qd * 8];
      float4 rB = *(const float4*)&rstdL[k0 + Qd * 8 + 4];
      union { uint4 q; unsigned short us[8]; } u;
      u.q = v;
      float x0 = fmaxf((bf2f(u.us[0]) - mA.x) * rA.x, 0.f);
      float x1 = fmaxf((bf2f(u.us[1]) - mA.y) * rA.y, 0.f);
      float x2 = fmaxf((bf2f(u.us[2]) - mA.z) * rA.z, 0.f);
      float x3 = fmaxf((bf2f(u.us[3]) - mA.w) * rA.w, 0.f);
      float x4 = fmaxf((bf2f(u.us[4]) - mB.x) * rB.x, 0.f);
      float x5 = fmaxf((bf2f(u.us[5]) - mB.y) * rB.y, 0.f);
      float x6 = fmaxf((bf2f(u.us[6]) - mB.z) * rB.z, 0.f);
      float x7 = fmaxf((bf2f(u.us[7]) - mB.w) * rB.w, 0.f);
      u.q.x = pk2(x0, x1); u.q.y = pk2(x2, x3);
      u.q.z = pk2(x4, x5); u.q.w = pk2(x6, x7);
      v = u.q;
    }
    union { uint4 q; bf16x8 b; } bc;
    bc.q = v;
#pragma unroll
    for (int mt = 0; mt < 4; ++mt)
      acc[mt] = __builtin_amdgcn_mfma_f32_16x16x32_bf16(af[mt], bc.b, acc[mt], 0, 0, 0);
  }

#pragma unroll
  for (int mt = 0; mt < 4; ++mt) {
    const int c0 = bm + mt * 16 + Qd * 4;
    const float b0 = g.bias[c0], b1 = g.bias[c0 + 1];
    const float b2 = g.bias[c0 + 2], b3 = g.bias[c0 + 3];
    f32x4 a = acc[mt];
    float v0 = a[0] + b0, v1 = a[1] + b1, v2 = a[2] + b2, v3 = a[3] + b3;
    if (g.mode <= 2) {
      if (g.mode == 0) {
        const float sc = 0.25503488f;  // 1/sqrt(32)*log2e
        v0 *= sc; v1 *= sc; v2 *= sc; v3 *= sc;
      }
      const int d = c0 >> 2;
      if (g.mode == 1) {
        g.Cb[((size_t)0 * NN + n) * 32 + d] = (unsigned short)f2bf(v0);
        g.Cb[((size_t)1 * NN + n) * 32 + d] = (unsigned short)f2bf(v1);
        g.Cb[((size_t)2 * NN + n) * 32 + d] = (unsigned short)f2bf(v2);
        g.Cb[((size_t)3 * NN + n) * 32 + d] = (unsigned short)f2bf(v3);
      } else {
        g.Cb[(size_t)(0 * 32 + d) * NN + n] = (unsigned short)f2bf(v0);
        g.Cb[(size_t)(1 * 32 + d) * NN + n] = (unsigned short)f2bf(v1);
        g.Cb[(size_t)(2 * 32 + d) * NN + n] = (unsigned short)f2bf(v2);
        g.Cb[(size_t)(3 * 32 + d) * NN + n] = (unsigned short)f2bf(v3);
      }
    } else if (g.mode == 5) {
      uint2 pv = { pk2(v0, v1), pk2(v2, v3) };
      *(uint2*)&g.Cb[(size_t)n * g.ldc + c0] = pv;
      float sA[4] = {v0, v1, v2, v3};
      float sQ[4] = {v0 * v0, v1 * v1, v2 * v2, v3 * v3};
#pragma unroll
      for (int r = 0; r < 4; ++r) {
#pragma unroll
        for (int off = 1; off < 16; off <<= 1) {
          sA[r] += __shfl_xor(sA[r], off);
          sQ[r] += __shfl_xor(sQ[r], off);
        }
      }
      if (col == 0) {
#pragma unroll
        for (int r = 0; r < 4; ++r) {
          swS[w][mt * 16 + Qd * 4 + r] = sA[r];
          swQ[w][mt * 16 + Qd * 4 + r] = sQ[r];
        }
      }
    } else {  // mode 4
      float* dp = g.Cf;
      float o0 = dp[(size_t)(c0 + 0) * NN + n] + v0;
      float o1 = dp[(size_t)(c0 + 1) * NN + n] + v1;
      float o2 = dp[(size_t)(c0 + 2) * NN + n] + v2;
      float o3 = dp[(size_t)(c0 + 3) * NN + n] + v3;
      dp[(size_t)(c0 + 0) * NN + n] = o0;
      dp[(size_t)(c0 + 1) * NN + n] = o1;
      dp[(size_t)(c0 + 2) * NN + n] = o2;
      dp[(size_t)(c0 + 3) * NN + n] = o3;
      uint2 pv = { pk2(o0, o1), pk2(o2, o3) };
      *(uint2*)&g.Cb[(size_t)n * g.ldc + c0] = pv;
    }
  }
  if (g.mode == 5) {
    __syncthreads();
    if (t < 64) {
      float a = swS[0][t] + swS[1][t] + swS[2][t] + swS[3][t];
      float b = swQ[0][t] + swQ[1][t] + swQ[2][t] + swQ[3][t];
      atomicAdd(&g.Cf[(bm + t) * 2], a);
      atomicAdd(&g.Cf[(bm + t) * 2 + 1], b);
    }
  }
}

// ---------------------------------------------------------------------------
// MFMA flash attention: single-pass online softmax, direct-fragment K/V
// loads, wave-private key quarters, barrier-free loop.
// Grid: (128 q-tiles of 16, 8 = desc*4+head). Block 256 = 4 waves.
// ---------------------------------------------------------------------------
__global__ __launch_bounds__(256, 4) void attn_mfma_kernel(
    const unsigned short* __restrict__ Qb0, const unsigned short* __restrict__ Kt0,
    const unsigned short* __restrict__ Vb0, const unsigned short* __restrict__ Qb1,
    const unsigned short* __restrict__ Kt1, const unsigned short* __restrict__ Vb1,
    unsigned short* __restrict__ mgT0, unsigned short* __restrict__ mgT1, int cross) {
  const int z = blockIdx.y, desc = z >> 2, h = z & 3;
  const int t = threadIdx.x;
  const int wid = t >> 6, lane = t & 63;
  const int col = lane & 15, Qd = lane >> 4;
  const int qb = blockIdx.x * 16;

  const unsigned short* Qb = desc ? Qb1 : Qb0;
  const int s = cross ? (1 - desc) : desc;
  const unsigned short* Kt = s ? Kt1 : Kt0;
  const unsigned short* Vb = s ? Vb1 : Vb0;

  __shared__ __align__(16) unsigned short SM[7424];
  unsigned short* PW = SM + wid * 640;
  float* fS = (float*)(SM + 2560);

  bf16x8 bq;
  {
    union { unsigned short u[8]; bf16x8 v; } tmp;
#pragma unroll
    for (int j = 0; j < 8; ++j)
      tmp.u[j] = Qb[(size_t)(h * 32 + Qd * 8 + j) * NN + qb + col];
    bq = tmp.v;
  }

  f32x4 o0 = {0.f, 0.f, 0.f, 0.f}, o1 = {0.f, 0.f, 0.f, 0.f};
  float m = -1e30f, l = 0.f;

  const int kq = wid * 512;
#pragma unroll 2
  for (int it = 0; it < 16; ++it) {
    const int k0 = kq + it * 32;
    bf16x8 aK0 = *(const bf16x8*)&Kt[((size_t)h * NN + k0 + col) * 32 + Qd * 8];
    bf16x8 aK1 = *(const bf16x8*)&Kt[((size_t)h * NN + k0 + 16 + col) * 32 + Qd * 8];
    bf16x8 av0 = *(const bf16x8*)&Vb[(size_t)(h * 32 + col) * NN + k0 + Qd * 8];
    bf16x8 av1 = *(const bf16x8*)&Vb[(size_t)(h * 32 + 16 + col) * NN + k0 + Qd * 8];
    f32x4 z4 = {0.f, 0.f, 0.f, 0.f};
    f32x4 s0 = __builtin_amdgcn_mfma_f32_16x16x32_bf16(aK0, bq, z4, 0, 0, 0);
    f32x4 s1 = __builtin_amdgcn_mfma_f32_16x16x32_bf16(aK1, bq, z4, 0, 0, 0);
    float cm = fmaxf(fmaxf(fmaxf(s0[0], s0[1]), fmaxf(s0[2], s0[3])),
                     fmaxf(fmaxf(s1[0], s1[1]), fmaxf(s1[2], s1[3])));
    cm = fmaxf(cm, __shfl_xor(cm, 16));
    cm = fmaxf(cm, __shfl_xor(cm, 32));
    const float mn = fmaxf(m, cm);
    const float alpha = exp2f(m - mn);
    m = mn;
    float p00 = exp2f(s0[0] - mn), p01 = exp2f(s0[1] - mn);
    float p02 = exp2f(s0[2] - mn), p03 = exp2f(s0[3] - mn);
    float p10 = exp2f(s1[0] - mn), p11 = exp2f(s1[1] - mn);
    float p12 = exp2f(s1[2] - mn), p13 = exp2f(s1[3] - mn);
    float us = (p00 + p01) + (p02 + p03) + (p10 + p11) + (p12 + p13);
    us += __shfl_xor(us, 16);
    us += __shfl_xor(us, 32);
    l = l * alpha + us;
    uint2 w0 = { pk2(p00, p01), pk2(p02, p03) };
    uint2 w1 = { pk2(p10, p11), pk2(p12, p13) };
    *(uint2*)&PW[col * 40 + Qd * 4] = w0;
    *(uint2*)&PW[col * 40 + 16 + Qd * 4] = w1;
    bf16x8 pb = *(const bf16x8*)&PW[col * 40 + Qd * 8];
    o0 = o0 * alpha;
    o1 = o1 * alpha;
    o0 = __builtin_amdgcn_mfma_f32_16x16x32_bf16(av0, pb, o0, 0, 0, 0);
    o1 = __builtin_amdgcn_mfma_f32_16x16x32_bf16(av1, pb, o1, 0, 0, 0);
  }

  __syncthreads();
  *(float4*)&fS[wid * 576 + col * 36 + Qd * 4] =
      make_float4(o0[0], o0[1], o0[2], o0[3]);
  *(float4*)&fS[wid * 576 + col * 36 + 16 + Qd * 4] =
      make_float4(o1[0], o1[1], o1[2], o1[3]);
  if (Qd == 0) {
    fS[2304 + wid * 16 + col] = m;
    fS[2368 + wid * 16 + col] = l;
  }
  __syncthreads();
  {
    const int q16 = t >> 4, dg = t & 15;
    float m0 = fS[2304 + q16], m1 = fS[2304 + 16 + q16];
    float m2 = fS[2304 + 32 + q16], m3 = fS[2304 + 48 + q16];
    float M = fmaxf(fmaxf(m0, m1), fmaxf(m2, m3));
    float w0 = exp2f(m0 - M), w1 = exp2f(m1 - M);
    float w2 = exp2f(m2 - M), w3 = exp2f(m3 - M);
    float L = w0 * fS[2368 + q16] + w1 * fS[2368 + 16 + q16] +
              w2 * fS[2368 + 32 + q16] + w3 * fS[2368 + 48 + q16];
    float inv = 1.0f / L;
    unsigned short* T = desc ? mgT1 : mgT0;
    const int q = qb + q16;
#pragma unroll
    for (int r = 0; r < 2; ++r) {
      int d = dg * 2 + r;
      float v = (w0 * fS[0 * 576 + q16 * 36 + d] + w1 * fS[1 * 576 + q16 * 36 + d] +
                 w2 * fS[2 * 576 + q16 * 36 + d] + w3 * fS[3 * 576 + q16 * 36 + d]) * inv;
      T[(size_t)q * 128 + d * 4 + h] = (unsigned short)f2bf(v);
    }
  }
}

// ---------------------------------------------------------------------------
// Fused tail: mlp2(layer l) + QKV(layer l+1) in one kernel.
// Grid (128 n-tiles of 16, 2 desc) = 256 blocks, 4 waves.
// ---------------------------------------------------------------------------
struct FDesc {
  const unsigned short* HT; const float* Sp; float* outF; unsigned short* dT;
  unsigned short* Qb; unsigned short* Kt; unsigned short* Vb;
};
struct FArgs {
  FDesc d[2];
  const unsigned short *W2l, *Wql, *Wkl, *Wvl;
  const float *b2l, *bql, *bkl, *bvl;
};

__global__ __launch_bounds__(256) void fused_tail_kernel(FArgs F) {
  const FDesc g = F.d[blockIdx.y];
  const int t = threadIdx.x;
  const int w = t >> 6, lane = t & 63;
  const int col = lane & 15, Qd = lane >> 4;
  const int nb = blockIdx.x * 16;
  const int n = nb + col;

  __shared__ float meanL[256], rstdL[256];
  __shared__ __align__(16) unsigned short dTs[16 * 136];

  {
    float s = g.Sp[t * 2], ss = g.Sp[t * 2 + 1];
    float mean = s * (1.0f / NN);
    float var = fmaxf(ss * (1.0f / NN) - mean * mean, 0.f);
    meanL[t] = mean;
    rstdL[t] = rsqrtf(var + 1e-5f);
  }
  __syncthreads();

  f32x4 accA[2];
  accA[0] = (f32x4){0.f, 0.f, 0.f, 0.f};
  accA[1] = (f32x4){0.f, 0.f, 0.f, 0.f};
#pragma unroll
  for (int k0 = 0; k0 < 256; k0 += 32) {
    uint4 v = *(const uint4*)&g.HT[(size_t)n * 256 + k0 + Qd * 8];
    float4 mA = *(const float4*)&meanL[k0 + Qd * 8];
    float4 mB = *(const float4*)&meanL[k0 + Qd * 8 + 4];
    float4 rA = *(const float4*)&rstdL[k0 + Qd * 8];
    float4 rB = *(const float4*)&rstdL[k0 + Qd * 8 + 4];
    union { uint4 q; unsigned short us[8]; } u;
    u.q = v;
    float x0 = fmaxf((bf2f(u.us[0]) - mA.x) * rA.x, 0.f);
    float x1 = fmaxf((bf2f(u.us[1]) - mA.y) * rA.y, 0.f);
    float x2 = fmaxf((bf2f(u.us[2]) - mA.z) * rA.z, 0.f);
    float x3 = fmaxf((bf2f(u.us[3]) - mA.w) * rA.w, 0.f);
    float x4 = fmaxf((bf2f(u.us[4]) - mB.x) * rB.x, 0.f);
    float x5 = fmaxf((bf2f(u.us[5]) - mB.y) * rB.y, 0.f);
    float x6 = fmaxf((bf2f(u.us[6]) - mB.z) * rB.z, 0.f);
    float x7 = fmaxf((bf2f(u.us[7]) - mB.w) * rB.w, 0.f);
    u.q.x = pk2(x0, x1); u.q.y = pk2(x2, x3);
    u.q.z = pk2(x4, x5); u.q.w = pk2(x6, x7);
    union { uint4 q; bf16x8 b; } bc;
    bc.q = u.q;
#pragma unroll
    for (int mt = 0; mt < 2; ++mt) {
      bf16x8 af = *(const bf16x8*)&F.W2l[(size_t)(w * 32 + mt * 16 + col) * 256 + k0 + Qd * 8];
      accA[mt] = __builtin_amdgcn_mfma_f32_16x16x32_bf16(af, bc.b, accA[mt], 0, 0, 0);
    }
  }
#pragma unroll
  for (int mt = 0; mt < 2; ++mt) {
    const int c0 = w * 32 + mt * 16 + Qd * 4;
    f32x4 a = accA[mt];
    float o0 = g.outF[(size_t)(c0 + 0) * NN + n] + a[0] + F.b2l[c0 + 0];
    float o1 = g.outF[(size_t)(c0 + 1) * NN + n] + a[1] + F.b2l[c0 + 1];
    float o2 = g.outF[(size_t)(c0 + 2) * NN + n] + a[2] + F.b2l[c0 + 2];
    float o3 = g.outF[(size_t)(c0 + 3) * NN + n] + a[3] + F.b2l[c0 + 3];
    g.outF[(size_t)(c0 + 0) * NN + n] = o0;
    g.outF[(size_t)(c0 + 1) * NN + n] = o1;
    g.outF[(size_t)(c0 + 2) * NN + n] = o2;
    g.outF[(size_t)(c0 + 3) * NN + n] = o3;
    unsigned short s0 = (unsigned short)f2bf(o0), s1 = (unsigned short)f2bf(o1);
    unsigned short s2 = (unsigned short)f2bf(o2), s3 = (unsigned short)f2bf(o3);
    dTs[col * 136 + c0 + 0] = s0;
    dTs[col * 136 + c0 + 1] = s1;
    dTs[col * 136 + c0 + 2] = s2;
    dTs[col * 136 + c0 + 3] = s3;
    uint2 pv = { ((unsigned int)s0) | (((unsigned int)s1) << 16),
                 ((unsigned int)s2) | (((unsigned int)s3) << 16) };
    *(uint2*)&g.dT[(size_t)n * 128 + c0] = pv;
  }
  __syncthreads();

  f32x4 accB[6];
#pragma unroll
  for (int f = 0; f < 6; ++f) accB[f] = (f32x4){0.f, 0.f, 0.f, 0.f};
#pragma unroll
  for (int k0 = 0; k0 < 128; k0 += 32) {
    bf16x8 bq = *(const bf16x8*)&dTs[col * 136 + k0 + Qd * 8];
#pragma unroll
    for (int f = 0; f < 6; ++f) {
      const int idx = w * 6 + f;
      const int op = idx >> 3, mt = idx & 7;
      const unsigned short* W = (op == 0) ? F.Wql : (op == 1) ? F.Wkl : F.Wvl;
      bf16x8 af = *(const bf16x8*)&W[(size_t)(mt * 16 + col) * 128 + k0 + Qd * 8];
      accB[f] = __builtin_amdgcn_mfma_f32_16x16x32_bf16(af, bq, accB[f], 0, 0, 0);
    }
  }
#pragma unroll
  for (int f = 0; f < 6; ++f) {
    const int idx = w * 6 + f;
    const int op = idx >> 3, mt = idx & 7;
    const float* bias = (op == 0) ? F.bql : (op == 1) ? F.bkl : F.bvl;
    const int c0 = mt * 16 + Qd * 4;
    f32x4 a = accB[f];
    float v0 = a[0] + bias[c0], v1 = a[1] + bias[c0 + 1];
    float v2 = a[2] + bias[c0 + 2], v3 = a[3] + bias[c0 + 3];
    const int d = c0 >> 2;
    if (op == 0) {
      const float sc = 0.25503488f;  // 1/sqrt(32)*log2e
      v0 *= sc; v1 *= sc; v2 *= sc; v3 *= sc;
      g.Qb[(size_t)(0 * 32 + d) * NN + n] = (unsigned short)f2bf(v0);
      g.Qb[(size_t)(1 * 32 + d) * NN + n] = (unsigned short)f2bf(v1);
      g.Qb[(size_t)(2 * 32 + d) * NN + n] = (unsigned short)f2bf(v2);
      g.Qb[(size_t)(3 * 32 + d) * NN + n] = (unsigned short)f2bf(v3);
    } else if (op == 1) {
      g.Kt[((size_t)0 * NN + n) * 32 + d] = (unsigned short)f2bf(v0);
      g.Kt[((size_t)1 * NN + n) * 32 + d] = (unsigned short)f2bf(v1);
      g.Kt[((size_t)2 * NN + n) * 32 + d] = (unsigned short)f2bf(v2);
      g.Kt[((size_t)3 * NN + n) * 32 + d] = (unsigned short)f2bf(v3);
    } else {
      g.Vb[(size_t)(0 * 32 + d) * NN + n] = (unsigned short)f2bf(v0);
      g.Vb[(size_t)(1 * 32 + d) * NN + n] = (unsigned short)f2bf(v1);
      g.Vb[(size_t)(2 * 32 + d) * NN + n] = (unsigned short)f2bf(v2);
      g.Vb[(size_t)(3 * 32 + d) * NN + n] = (unsigned short)f2bf(v3);
    }
  }
}

// ---------------------------------------------------------------------------
extern "C" void kernel_launch(void* const* d_in, const int* in_sizes, int n_in,
                              void* d_out, int out_size, void* d_ws, size_t ws_size,
                              hipStream_t stream) {
  const float* desc0 = (const float*)d_in[0];
  const float* desc1 = (const float*)d_in[1];
  const float* Wq = (const float*)d_in[2];
  const float* bq = (const float*)d_in[3];
  const float* Wk = (const float*)d_in[4];
  const float* bk = (const float*)d_in[5];
  const float* Wv = (const float*)d_in[6];
  const float* bv = (const float*)d_in[7];
  const float* Wm = (const float*)d_in[8];
  const float* bmv = (const float*)d_in[9];
  const float* W1 = (const float*)d_in[10];
  const float* b1 = (const float*)d_in[11];
  const float* W2 = (const float*)d_in[12];
  const float* b2 = (const float*)d_in[13];

  float* out0 = (float*)d_out;
  float* out1 = out0 + (size_t)DDIM * NN;

  float* fws = (float*)d_ws;
  float* SgAll = fws;                  // 6 x 1024
  float* b1m = SgAll + 6144;           // 1536
  unsigned short* uws = (unsigned short*)(b1m + 1536);
  unsigned short* dT0 = uws;                     // 262144 each
  unsigned short* dT1 = uws + 1 * 262144;
  unsigned short* Qb0 = uws + 2 * 262144;
  unsigned short* Qb1 = uws + 3 * 262144;
  unsigned short* Kt0 = uws + 4 * 262144;
  unsigned short* Kt1 = uws + 5 * 262144;
  unsigned short* Vb0 = uws + 6 * 262144;
  unsigned short* Vb1 = uws + 7 * 262144;
  unsigned short* mgT0 = uws + 8 * 262144;
  unsigned short* mgT1 = uws + 9 * 262144;
  unsigned short* HT0 = uws + 10 * 262144;       // 524288
  unsigned short* HT1 = HT0 + 524288;            // 524288
  unsigned short* Wqkv = HT1 + 524288;           // 294912
  unsigned short* Wb2 = Wqkv + 294912;           // 196608
  unsigned short* Wmix = Wb2 + 196608;           // 393216

  setup_kernel<<<790, 256, 0, stream>>>(Wq, Wk, Wv, Wm, W1, W2, bmv, b1,
                                        desc0, desc1, Wqkv, Wb2, Wmix, b1m,
                                        dT0, dT1, out0, out1, SgAll);

  // layer-0 QKV (standalone)
  {
    MOps8 Pq = {};
    Pq.op[0] = {Wqkv, bq, dT0, nullptr, Qb0, nullptr, nullptr, 128, 0, 0};
    Pq.op[1] = {Wqkv, bq, dT1, nullptr, Qb1, nullptr, nullptr, 128, 0, 0};
    Pq.op[2] = {Wqkv + 98304, bk, dT0, nullptr, Kt0, nullptr, nullptr, 128, 0, 1};
    Pq.op[3] = {Wqkv + 98304, bk, dT1, nullptr, Kt1, nullptr, nullptr, 128, 0, 1};
    Pq.op[4] = {Wqkv + 196608, bv, dT0, nullptr, Vb0, nullptr, nullptr, 128, 0, 2};
    Pq.op[5] = {Wqkv + 196608, bv, dT1, nullptr, Vb1, nullptr, nullptr, 128, 0, 2};
    gemm_direct_kernel<128><<<dim3(32, 2, 6), 256, 0, stream>>>(Pq);
  }

  for (int l = 0; l < NL; ++l) {
    const unsigned short* w2 = Wb2 + l * 32768;
    const float* b2p = b2 + (size_t)l * 128;
    float* Sg0 = SgAll + l * 1024;
    float* Sg1 = Sg0 + 512;

    attn_mfma_kernel<<<dim3(128, 8), 256, 0, stream>>>(
        Qb0, Kt0, Vb0, Qb1, Kt1, Vb1, mgT0, mgT1, l & 1);

    MOps8 P1 = {};
    P1.op[0] = {Wmix + l * 65536, b1m + (size_t)l * 256, dT0, mgT0, HT0, Sg0, nullptr, 128, 256, 5};
    P1.op[1] = {Wmix + l * 65536, b1m + (size_t)l * 256, dT1, mgT1, HT1, Sg1, nullptr, 128, 256, 5};
    gemm_direct_kernel<256><<<dim3(32, 4, 2), 256, 0, stream>>>(P1);

    if (l < NL - 1) {
      FArgs F;
      F.d[0] = {HT0, Sg0, out0, dT0, Qb0, Kt0, Vb0};
      F.d[1] = {HT1, Sg1, out1, dT1, Qb1, Kt1, Vb1};
      F.W2l = w2;
      F.Wql = Wqkv + (l + 1) * 16384;
      F.Wkl = Wqkv + 98304 + (l + 1) * 16384;
      F.Wvl = Wqkv + 196608 + (l + 1) * 16384;
      F.b2l = b2p;
      F.bql = bq + (size_t)(l + 1) * 128;
      F.bkl = bk + (size_t)(l + 1) * 128;
      F.bvl = bv + (size_t)(l + 1) * 128;
      fused_tail_kernel<<<dim3(128, 2), 256, 0, stream>>>(F);
    } else {
      MOps8 P2 = {};
      P2.op[0] = {w2, b2p, HT0, nullptr, dT0, out0, Sg0, 256, 128, 4};
      P2.op[1] = {w2, b2p, HT1, nullptr, dT1, out1, Sg1, 256, 128, 4};
      gemm_direct_kernel<256><<<dim3(32, 2, 2), 256, 0, stream>>>(P2);
    }
  }
}